// Round 1
// baseline (266.747 us; speedup 1.0000x reference)
//
#include <hip/hip_runtime.h>
#include <hip/hip_bf16.h>
#include <math.h>

#define DEV __device__ __forceinline__

typedef __attribute__((ext_vector_type(4))) float f32x4;
typedef __attribute__((ext_vector_type(8))) short bf16x8;     // 8 bf16 in 4 VGPRs (MFMA frag)
typedef __attribute__((ext_vector_type(8))) unsigned short u16x8;
typedef unsigned short u16;
typedef unsigned int u32;

DEV u16 f2bf(float f) {
  union { float f; u32 u; } v; v.f = f;
  u32 r = v.u + 0x7fffu + ((v.u >> 16) & 1u);
  return (u16)(r >> 16);
}
DEV float bf2f(u16 h) {
  union { u32 u; float f; } v; v.u = ((u32)h) << 16;
  return v.f;
}

DEV void gl_lds16(const u16* g, u16* s) {
  __builtin_amdgcn_global_load_lds((const __attribute__((address_space(1))) void*)g,
                                   (__attribute__((address_space(3))) void*)s, 16, 0, 0);
}

#define MFMA16(a, b, c) __builtin_amdgcn_mfma_f32_16x16x32_bf16((a), (b), (c), 0, 0, 0)

// ---------------------------------------------------------------------------
// Prep: cast src + weights to bf16; concat wq|wk|wv|wg -> Wcat (k scaled 0.125);
// concat biases bq|bk*0.125|bv|bg -> bcat.
// ---------------------------------------------------------------------------
DEV void cast8(const float* in, u16* out, float s) {
  f32x4 a = *(const f32x4*)in;
  f32x4 b = *(const f32x4*)(in + 4);
  u16x8 r;
  r[0] = f2bf(a[0] * s); r[1] = f2bf(a[1] * s); r[2] = f2bf(a[2] * s); r[3] = f2bf(a[3] * s);
  r[4] = f2bf(b[0] * s); r[5] = f2bf(b[1] * s); r[6] = f2bf(b[2] * s); r[7] = f2bf(b[3] * s);
  *(u16x8*)out = r;
}

__global__ __launch_bounds__(256) void prep_cast(
    const float* __restrict__ src, const float* __restrict__ wq, const float* __restrict__ wk,
    const float* __restrict__ wv, const float* __restrict__ wg, const float* __restrict__ wo,
    const float* __restrict__ fc1, const float* __restrict__ fc2,
    const float* __restrict__ bq, const float* __restrict__ bk,
    const float* __restrict__ bv, const float* __restrict__ bg,
    u16* __restrict__ src_bf, u16* __restrict__ Wcat, u16* __restrict__ wo_bf,
    u16* __restrict__ fc1_bf, u16* __restrict__ fc2_bf, float* __restrict__ bcat) {
  int u = blockIdx.x * 256 + threadIdx.x;
  if (u < 524288) {
    cast8(src + (size_t)u * 8, src_bf + (size_t)u * 8, 1.0f);
  } else if (u < 557056) {
    int v = u - 524288; cast8(wq + (size_t)v * 8, Wcat + (size_t)v * 8, 1.0f);
  } else if (u < 589824) {
    int v = u - 557056; cast8(wk + (size_t)v * 8, Wcat + 262144 + (size_t)v * 8, 0.125f);
  } else if (u < 622592) {
    int v = u - 589824; cast8(wv + (size_t)v * 8, Wcat + 524288 + (size_t)v * 8, 1.0f);
  } else if (u < 655360) {
    int v = u - 622592; cast8(wg + (size_t)v * 8, Wcat + 786432 + (size_t)v * 8, 1.0f);
  } else if (u < 688128) {
    int v = u - 655360; cast8(wo + (size_t)v * 8, wo_bf + (size_t)v * 8, 1.0f);
  } else if (u < 819200) {
    int v = u - 688128; cast8(fc1 + (size_t)v * 8, fc1_bf + (size_t)v * 8, 1.0f);
  } else if (u < 950272) {
    int v = u - 819200; cast8(fc2 + (size_t)v * 8, fc2_bf + (size_t)v * 8, 1.0f);
  } else if (u < 950528) {
    int v = u - 950272;
    #pragma unroll
    for (int e = 0; e < 8; e++) {
      int c = v * 8 + e;
      float val;
      if (c < 512)       val = bq[c];
      else if (c < 1024) val = bk[c - 512] * 0.125f;
      else if (c < 1536) val = bv[c - 1024];
      else               val = bg[c - 1536];
      bcat[c] = val;
    }
  }
}

// ---------------------------------------------------------------------------
// GEMM: C = A(MxK bf16, row-major) @ W^T (W is NxK bf16 row-major) + bias.
// 128x128 tile, BK=32, 4 waves (2x2 of 64x64), 16x16x32 bf16 MFMA.
// ACT: 0=none, 1=exact gelu. OB: write bf16 out. OF: write fp32 out.
// ---------------------------------------------------------------------------
template <int ACT, int OB, int OF>
__global__ __launch_bounds__(256) void gemm_bf16(
    const u16* __restrict__ A, const u16* __restrict__ W, const float* __restrict__ bias,
    u16* __restrict__ Ob, float* __restrict__ Of, int M, int N, int K) {
  __shared__ __align__(16) u16 As[128 * 32];
  __shared__ __align__(16) u16 Ws[128 * 32];
  const int t = threadIdx.x, l = t & 63;
  const int w = t >> 6, wr = (w >> 1) * 64, wc = (w & 1) * 64;
  const int bm = blockIdx.y * 128, bn = blockIdx.x * 128;
  const int lr = (l >> 4) * 4, lc = l & 15;

  f32x4 acc[4][4] = {};

  const int c0 = t, c1 = t + 256;
  const u16* gA0 = A + (size_t)(bm + (c0 >> 2)) * K + (c0 & 3) * 8;
  const u16* gA1 = A + (size_t)(bm + (c1 >> 2)) * K + (c1 & 3) * 8;
  const u16* gW0 = W + (size_t)(bn + (c0 >> 2)) * K + (c0 & 3) * 8;
  const u16* gW1 = W + (size_t)(bn + (c1 >> 2)) * K + (c1 & 3) * 8;
  u16* sA0 = &As[c0 * 8]; u16* sA1 = &As[c1 * 8];
  u16* sW0 = &Ws[c0 * 8]; u16* sW1 = &Ws[c1 * 8];

  for (int kt = 0; kt < K; kt += 32) {
    gl_lds16(gA0 + kt, sA0);
    gl_lds16(gA1 + kt, sA1);
    gl_lds16(gW0 + kt, sW0);
    gl_lds16(gW1 + kt, sW1);
    __syncthreads();
    bf16x8 af[4], bfr[4];
    #pragma unroll
    for (int i = 0; i < 4; i++)
      af[i] = *(const bf16x8*)&As[(wr + i * 16 + lc) * 32 + ((l >> 4) << 3)];
    #pragma unroll
    for (int i = 0; i < 4; i++)
      bfr[i] = *(const bf16x8*)&Ws[(wc + i * 16 + lc) * 32 + ((l >> 4) << 3)];
    #pragma unroll
    for (int mi = 0; mi < 4; mi++)
      #pragma unroll
      for (int ni = 0; ni < 4; ni++)
        acc[mi][ni] = MFMA16(af[mi], bfr[ni], acc[mi][ni]);
    __syncthreads();
  }

  #pragma unroll
  for (int ni = 0; ni < 4; ni++) {
    int col = bn + wc + ni * 16 + lc;
    float bb = bias[col];
    #pragma unroll
    for (int mi = 0; mi < 4; mi++) {
      #pragma unroll
      for (int r = 0; r < 4; r++) {
        int row = bm + wr + mi * 16 + lr + r;
        float v = acc[mi][ni][r] + bb;
        if (ACT == 1) v = 0.5f * v * (1.0f + erff(v * 0.70710678118f));
        if (OB) Ob[(size_t)row * N + col] = f2bf(v);
        if (OF) Of[(size_t)row * N + col] = v;
      }
    }
  }
}

// ---------------------------------------------------------------------------
// Retention: per block = one (b,h) x 64 query rows. Full j-loop (no mask in ref).
// qk = q@k^T + dm (analytic decay), den = max(|rowsum(qk)|,1),
// o = (qk@v)/den -> per-head LN(eps=1e-6) -> silu(g)*o -> gated (8192x512) bf16.
// ---------------------------------------------------------------------------
__global__ __launch_bounds__(256) void retention_kernel(
    const u16* __restrict__ qkvg, u16* __restrict__ gated) {
  const int S = 2048, DD = 2048;
  const int rb = blockIdx.x * 64;
  const int bh = blockIdx.y, b = bh >> 3, h = bh & 7;
  const int t = threadIdx.x, l = t & 63, w = t >> 6;
  const int lr = (l >> 4) * 4, lc = l & 15;
  const int wrow = rb + w * 16;

  __shared__ __align__(16) u16 Ks[64 * 72];
  __shared__ __align__(16) u16 Vt[64 * 72];
  __shared__ __align__(16) u16 Ps[4][16 * 72];

  const size_t base = (size_t)b * S * DD + (size_t)h * 64;
  const u16* qp = qkvg + base;
  const u16* kp = qkvg + base + 512;
  const u16* vp = qkvg + base + 1024;
  const u16* gp = qkvg + base + 1536;

  const float gamma = 1.0f - exp2f(-5.0f - (float)h);
  const float l2g = log2f(gamma);

  float ai[4];
  float acc_s[4] = {0.f, 0.f, 0.f, 0.f};
  #pragma unroll
  for (int r = 0; r < 4; r++) {
    int i = wrow + lr + r;
    float rowsum = (1.0f - exp2f((float)(i + 1) * l2g)) / (1.0f - gamma);
    ai[r] = exp2f((float)i * l2g) * rsqrtf(rowsum);
  }

  // Q fragments (A operand), constant over j loop
  bf16x8 qf0, qf1;
  {
    const u16* qrow = qp + (size_t)(wrow + lc) * DD + ((l >> 4) << 3);
    qf0 = *(const bf16x8*)qrow;
    qf1 = *(const bf16x8*)(qrow + 32);
  }

  f32x4 accO[4] = {};

  const int sc0 = t, sc1 = t + 256;       // K staging chunks
  const int vj = t & 63, vd = (t >> 6) * 16;  // V transpose staging

  for (int jt = 0; jt < S; jt += 64) {
    // stage K tile [64][72]
    {
      int r0 = sc0 >> 3, o0 = (sc0 & 7) << 3;
      *(u16x8*)&Ks[r0 * 72 + o0] = *(const u16x8*)(kp + (size_t)(jt + r0) * DD + o0);
      int r1 = sc1 >> 3, o1 = (sc1 & 7) << 3;
      *(u16x8*)&Ks[r1 * 72 + o1] = *(const u16x8*)(kp + (size_t)(jt + r1) * DD + o1);
    }
    // stage V transposed [d][j]
    {
      const u16* vr = vp + (size_t)(jt + vj) * DD + vd;
      u16x8 v0 = *(const u16x8*)vr;
      u16x8 v1 = *(const u16x8*)(vr + 8);
      #pragma unroll
      for (int e = 0; e < 8; e++) Vt[(vd + e) * 72 + vj] = v0[e];
      #pragma unroll
      for (int e = 0; e < 8; e++) Vt[(vd + 8 + e) * 72 + vj] = v1[e];
    }
    __syncthreads();

    // QK^T (16 rows x 64 cols per wave) + decay bias + row-sum + P->LDS
    #pragma unroll
    for (int nf = 0; nf < 4; nf++) {
      const u16* kb = &Ks[(nf * 16 + lc) * 72 + ((l >> 4) << 3)];
      bf16x8 kf0 = *(const bf16x8*)kb;
      bf16x8 kf1 = *(const bf16x8*)(kb + 32);
      f32x4 s = {0.f, 0.f, 0.f, 0.f};
      s = MFMA16(qf0, kf0, s);
      s = MFMA16(qf1, kf1, s);
      int jn = jt + nf * 16;
      int jc = jn + lc;
      if (jn <= wrow + 15) {
        float bj = exp2f(-(float)jc * l2g);
        if (jn + 15 <= wrow) {
          #pragma unroll
          for (int r = 0; r < 4; r++) s[r] += ai[r] * bj;
        } else {
          #pragma unroll
          for (int r = 0; r < 4; r++) {
            int i = wrow + lr + r;
            s[r] += (i >= jc) ? ai[r] * bj : 0.0f;
          }
        }
      }
      #pragma unroll
      for (int r = 0; r < 4; r++) {
        acc_s[r] += s[r];
        Ps[w][(lr + r) * 72 + nf * 16 + lc] = f2bf(s[r]);
      }
    }
    __syncthreads();

    // PV: O += P @ V
    bf16x8 pa0 = *(const bf16x8*)&Ps[w][lc * 72 + ((l >> 4) << 3)];
    bf16x8 pa1 = *(const bf16x8*)&Ps[w][lc * 72 + 32 + ((l >> 4) << 3)];
    #pragma unroll
    for (int nf = 0; nf < 4; nf++) {
      const u16* vb = &Vt[(nf * 16 + lc) * 72 + ((l >> 4) << 3)];
      bf16x8 vf0 = *(const bf16x8*)vb;
      bf16x8 vf1 = *(const bf16x8*)(vb + 32);
      accO[nf] = MFMA16(pa0, vf0, accO[nf]);
      accO[nf] = MFMA16(pa1, vf1, accO[nf]);
    }
    __syncthreads();
  }

  // row sums -> den
  #pragma unroll
  for (int r = 0; r < 4; r++) {
    float s = acc_s[r];
    s += __shfl_xor(s, 1); s += __shfl_xor(s, 2);
    s += __shfl_xor(s, 4); s += __shfl_xor(s, 8);
    acc_s[r] = s;
  }
  float o[4][4];  // [nf][r]
  #pragma unroll
  for (int r = 0; r < 4; r++) {
    float den = fmaxf(fabsf(acc_s[r]), 1.0f);
    float rden = 1.0f / den;
    #pragma unroll
    for (int nf = 0; nf < 4; nf++) o[nf][r] = accO[nf][r] * rden;
  }
  // per-head LayerNorm over 64 dims (eps 1e-6, no affine)
  float mu[4], rv[4];
  #pragma unroll
  for (int r = 0; r < 4; r++) {
    float s = o[0][r] + o[1][r] + o[2][r] + o[3][r];
    float s2 = o[0][r] * o[0][r] + o[1][r] * o[1][r] + o[2][r] * o[2][r] + o[3][r] * o[3][r];
    s  += __shfl_xor(s, 1);  s  += __shfl_xor(s, 2);  s  += __shfl_xor(s, 4);  s  += __shfl_xor(s, 8);
    s2 += __shfl_xor(s2, 1); s2 += __shfl_xor(s2, 2); s2 += __shfl_xor(s2, 4); s2 += __shfl_xor(s2, 8);
    mu[r] = s * (1.0f / 64.0f);
    float var = s2 * (1.0f / 64.0f) - mu[r] * mu[r];
    rv[r] = rsqrtf(var + 1e-6f);
  }
  // gate with silu(g) and store
  #pragma unroll
  for (int nf = 0; nf < 4; nf++) {
    #pragma unroll
    for (int r = 0; r < 4; r++) {
      int row = wrow + lr + r;
      int col = nf * 16 + lc;
      float gv = bf2f(gp[(size_t)row * DD + col]);
      float sg = gv / (1.0f + __expf(-gv));
      float val = (o[nf][r] - mu[r]) * rv[r] * sg;
      gated[((size_t)(b * S + row)) * 512 + h * 64 + col] = f2bf(val);
    }
  }
}

// ---------------------------------------------------------------------------
// x = LN(A + B) * gam + bet over D=512 (fp32). One wave per row.
// Optionally also writes bf16 copy.
// ---------------------------------------------------------------------------
__global__ __launch_bounds__(256) void add_ln512(
    const float* __restrict__ A, const float* __restrict__ Bv,
    const float* __restrict__ gam, const float* __restrict__ bet, float eps,
    float* __restrict__ Of, u16* __restrict__ Ob) {
  int row = blockIdx.x * 4 + (threadIdx.x >> 6);
  int l = threadIdx.x & 63;
  const float* a = A + (size_t)row * 512 + l * 8;
  const float* c = Bv + (size_t)row * 512 + l * 8;
  f32x4 a0 = *(const f32x4*)a, a1 = *(const f32x4*)(a + 4);
  f32x4 c0 = *(const f32x4*)c, c1 = *(const f32x4*)(c + 4);
  float x[8];
  #pragma unroll
  for (int e = 0; e < 4; e++) { x[e] = a0[e] + c0[e]; x[4 + e] = a1[e] + c1[e]; }
  float s = 0.f, s2 = 0.f;
  #pragma unroll
  for (int e = 0; e < 8; e++) { s += x[e]; s2 += x[e] * x[e]; }
  #pragma unroll
  for (int m = 1; m <= 32; m <<= 1) { s += __shfl_xor(s, m); s2 += __shfl_xor(s2, m); }
  float mu = s * (1.0f / 512.0f);
  float var = s2 * (1.0f / 512.0f) - mu * mu;
  float rinv = rsqrtf(var + eps);
  f32x4 g0 = *(const f32x4*)(gam + l * 8), g1 = *(const f32x4*)(gam + l * 8 + 4);
  f32x4 b0 = *(const f32x4*)(bet + l * 8), b1 = *(const f32x4*)(bet + l * 8 + 4);
  f32x4 y0, y1;
  #pragma unroll
  for (int e = 0; e < 4; e++) {
    y0[e] = (x[e] - mu) * rinv * g0[e] + b0[e];
    y1[e] = (x[4 + e] - mu) * rinv * g1[e] + b1[e];
  }
  float* op = Of + (size_t)row * 512 + l * 8;
  *(f32x4*)op = y0;
  *(f32x4*)(op + 4) = y1;
  if (Ob) {
    u16x8 rb_;
    #pragma unroll
    for (int e = 0; e < 4; e++) { rb_[e] = f2bf(y0[e]); rb_[4 + e] = f2bf(y1[e]); }
    *(u16x8*)(Ob + (size_t)row * 512 + l * 8) = rb_;
  }
}

// ---------------------------------------------------------------------------
// In-place sub-LN over FFN=2048 (bf16), eps 1e-6, affine. One wave per row.
// ---------------------------------------------------------------------------
__global__ __launch_bounds__(256) void subln_ffn(
    u16* __restrict__ hbuf, const float* __restrict__ gam, const float* __restrict__ bet) {
  int row = blockIdx.x * 4 + (threadIdx.x >> 6);
  int l = threadIdx.x & 63;
  u16* p = hbuf + (size_t)row * 2048;
  float x[32];
  #pragma unroll
  for (int cch = 0; cch < 4; cch++) {
    u16x8 v = *(const u16x8*)(p + cch * 512 + l * 8);
    #pragma unroll
    for (int e = 0; e < 8; e++) x[cch * 8 + e] = bf2f(v[e]);
  }
  float s = 0.f, s2 = 0.f;
  #pragma unroll
  for (int e = 0; e < 32; e++) { s += x[e]; s2 += x[e] * x[e]; }
  #pragma unroll
  for (int m = 1; m <= 32; m <<= 1) { s += __shfl_xor(s, m); s2 += __shfl_xor(s2, m); }
  float mu = s * (1.0f / 2048.0f);
  float var = s2 * (1.0f / 2048.0f) - mu * mu;
  float rinv = rsqrtf(var + 1e-6f);
  #pragma unroll
  for (int cch = 0; cch < 4; cch++) {
    int col = cch * 512 + l * 8;
    f32x4 g0 = *(const f32x4*)(gam + col), g1 = *(const f32x4*)(gam + col + 4);
    f32x4 b0 = *(const f32x4*)(bet + col), b1 = *(const f32x4*)(bet + col + 4);
    u16x8 o;
    #pragma unroll
    for (int e = 0; e < 4; e++) {
      o[e]     = f2bf((x[cch * 8 + e]     - mu) * rinv * g0[e] + b0[e]);
      o[4 + e] = f2bf((x[cch * 8 + 4 + e] - mu) * rinv * g1[e] + b1[e]);
    }
    *(u16x8*)(p + col) = o;
  }
}

// ---------------------------------------------------------------------------
extern "C" void kernel_launch(void* const* d_in, const int* in_sizes, int n_in,
                              void* d_out, int out_size, void* d_ws, size_t ws_size,
                              hipStream_t stream) {
  const float* src  = (const float*)d_in[0];
  const float* wq   = (const float*)d_in[3];
  const float* bq   = (const float*)d_in[4];
  const float* wk   = (const float*)d_in[5];
  const float* bk   = (const float*)d_in[6];
  const float* wv   = (const float*)d_in[7];
  const float* bv   = (const float*)d_in[8];
  const float* wg   = (const float*)d_in[9];
  const float* bg   = (const float*)d_in[10];
  const float* wo   = (const float*)d_in[11];
  const float* bo   = (const float*)d_in[12];
  const float* fc1w = (const float*)d_in[13];
  const float* fc1b = (const float*)d_in[14];
  const float* fc2w = (const float*)d_in[15];
  const float* fc2b = (const float*)d_in[16];
  const float* lng  = (const float*)d_in[17];
  const float* lnb  = (const float*)d_in[18];
  const float* n0g  = (const float*)d_in[19];
  const float* n0b  = (const float*)d_in[20];
  const float* n1g  = (const float*)d_in[21];
  const float* n1b  = (const float*)d_in[22];

  if (ws_size < 99098624u) return;  // need ~99.1 MB scratch

  char* ws = (char*)d_ws;
  u16*   src_bf = (u16*)(ws + 0);
  u16*   Wcat   = (u16*)(ws + 8388608);
  u16*   wo_bf  = (u16*)(ws + 10485760);
  u16*   fc1_bf = (u16*)(ws + 11010048);
  u16*   fc2_bf = (u16*)(ws + 13107200);
  float* bcat   = (float*)(ws + 15204352);
  u16*   qkvg   = (u16*)(ws + 15212544);   // 32 MB; reused as h1 after retention
  u16*   gated  = (u16*)(ws + 48766976);
  float* attn   = (float*)(ws + 57155584); // 16 MB; reused as y (fc2 out)
  float* xf     = (float*)(ws + 73932800);
  u16*   xbf    = (u16*)(ws + 90710016);

  // 1. casts / weight concat
  prep_cast<<<3713, 256, 0, stream>>>(src, wq, wk, wv, wg, wo, fc1w, fc2w,
                                      bq, bk, bv, bg,
                                      src_bf, Wcat, wo_bf, fc1_bf, fc2_bf, bcat);
  // 2. QKVG projection: (8192x512) @ (2048x512)^T
  gemm_bf16<0, 1, 0><<<dim3(16, 64), 256, 0, stream>>>(src_bf, Wcat, bcat, qkvg, nullptr,
                                                       8192, 2048, 512);
  // 3. retention + per-head LN + silu gating
  retention_kernel<<<dim3(32, 32), 256, 0, stream>>>(qkvg, gated);
  // 4. output projection
  gemm_bf16<0, 0, 1><<<dim3(4, 64), 256, 0, stream>>>(gated, wo_bf, bo, nullptr, attn,
                                                      8192, 512, 512);
  // 5. x = LN(src + attn), n0, eps 1e-5 -> fp32 + bf16
  add_ln512<<<2048, 256, 0, stream>>>(src, attn, n0g, n0b, 1e-5f, xf, xbf);
  // 6. fc1 + exact gelu -> h1 (aliases qkvg)
  gemm_bf16<1, 1, 0><<<dim3(16, 64), 256, 0, stream>>>(xbf, fc1_bf, fc1b, qkvg, nullptr,
                                                       8192, 2048, 512);
  // 7. sub-LN over 2048 (in place)
  subln_ffn<<<2048, 256, 0, stream>>>(qkvg, lng, lnb);
  // 8. fc2 -> y (aliases attn)
  gemm_bf16<0, 0, 1><<<dim3(4, 64), 256, 0, stream>>>(qkvg, fc2_bf, fc2b, nullptr, attn,
                                                      8192, 512, 2048);
  // 9. out = LN(x + y), n1, eps 1e-5 -> d_out (fp32)
  add_ln512<<<2048, 256, 0, stream>>>(xf, attn, n1g, n1b, 1e-5f, (float*)d_out, nullptr);
}

// Round 2
// 227.202 us; speedup vs baseline: 1.1741x; 1.1741x over previous
//
#include <hip/hip_runtime.h>
#include <hip/hip_bf16.h>
#include <math.h>

#define DEV __device__ __forceinline__

typedef __attribute__((ext_vector_type(4))) float f32x4;
typedef __attribute__((ext_vector_type(16))) float f32x16;
typedef __attribute__((ext_vector_type(8))) short bf16x8;     // 8 bf16 in 4 VGPRs (MFMA frag)
typedef __attribute__((ext_vector_type(8))) unsigned short u16x8;
typedef unsigned short u16;
typedef unsigned int u32;
typedef __attribute__((ext_vector_type(4))) u32 u32x4;

DEV u16 f2bf(float f) {
  union { float f; u32 u; } v; v.f = f;
  u32 r = v.u + 0x7fffu + ((v.u >> 16) & 1u);
  return (u16)(r >> 16);
}
DEV float bf2f(u16 h) {
  union { u32 u; float f; } v; v.u = ((u32)h) << 16;
  return v.f;
}

DEV void gl_lds16(const u16* g, u16* s) {
  __builtin_amdgcn_global_load_lds((const __attribute__((address_space(1))) void*)g,
                                   (__attribute__((address_space(3))) void*)s, 16, 0, 0);
}

DEV u32 cvt_pk_bf16(float lo, float hi) {
  u32 r;
  asm("v_cvt_pk_bf16_f32 %0, %1, %2" : "=v"(r) : "v"(lo), "v"(hi));
  return r;
}

DEV bf16x8 u4_to_bf8(u32x4 x) {
  union { u32x4 a; bf16x8 b; } u; u.a = x; return u.b;
}

#define MFMA16(a, b, c) __builtin_amdgcn_mfma_f32_16x16x32_bf16((a), (b), (c), 0, 0, 0)
#define MFMA32(a, b, c) __builtin_amdgcn_mfma_f32_32x32x16_bf16((a), (b), (c), 0, 0, 0)

// ---------------------------------------------------------------------------
// Prep: cast src + weights to bf16; concat wq|wk|wv|wg -> Wcat (k scaled 0.125);
// concat biases bq|bk*0.125|bv|bg -> bcat.
// ---------------------------------------------------------------------------
DEV void cast8(const float* in, u16* out, float s) {
  f32x4 a = *(const f32x4*)in;
  f32x4 b = *(const f32x4*)(in + 4);
  u16x8 r;
  r[0] = f2bf(a[0] * s); r[1] = f2bf(a[1] * s); r[2] = f2bf(a[2] * s); r[3] = f2bf(a[3] * s);
  r[4] = f2bf(b[0] * s); r[5] = f2bf(b[1] * s); r[6] = f2bf(b[2] * s); r[7] = f2bf(b[3] * s);
  *(u16x8*)out = r;
}

__global__ __launch_bounds__(256) void prep_cast(
    const float* __restrict__ src, const float* __restrict__ wq, const float* __restrict__ wk,
    const float* __restrict__ wv, const float* __restrict__ wg, const float* __restrict__ wo,
    const float* __restrict__ fc1, const float* __restrict__ fc2,
    const float* __restrict__ bq, const float* __restrict__ bk,
    const float* __restrict__ bv, const float* __restrict__ bg,
    u16* __restrict__ src_bf, u16* __restrict__ Wcat, u16* __restrict__ wo_bf,
    u16* __restrict__ fc1_bf, u16* __restrict__ fc2_bf, float* __restrict__ bcat) {
  int u = blockIdx.x * 256 + threadIdx.x;
  if (u < 524288) {
    cast8(src + (size_t)u * 8, src_bf + (size_t)u * 8, 1.0f);
  } else if (u < 557056) {
    int v = u - 524288; cast8(wq + (size_t)v * 8, Wcat + (size_t)v * 8, 1.0f);
  } else if (u < 589824) {
    int v = u - 557056; cast8(wk + (size_t)v * 8, Wcat + 262144 + (size_t)v * 8, 0.125f);
  } else if (u < 622592) {
    int v = u - 589824; cast8(wv + (size_t)v * 8, Wcat + 524288 + (size_t)v * 8, 1.0f);
  } else if (u < 655360) {
    int v = u - 622592; cast8(wg + (size_t)v * 8, Wcat + 786432 + (size_t)v * 8, 1.0f);
  } else if (u < 688128) {
    int v = u - 655360; cast8(wo + (size_t)v * 8, wo_bf + (size_t)v * 8, 1.0f);
  } else if (u < 819200) {
    int v = u - 688128; cast8(fc1 + (size_t)v * 8, fc1_bf + (size_t)v * 8, 1.0f);
  } else if (u < 950272) {
    int v = u - 819200; cast8(fc2 + (size_t)v * 8, fc2_bf + (size_t)v * 8, 1.0f);
  } else if (u < 950528) {
    int v = u - 950272;
    #pragma unroll
    for (int e = 0; e < 8; e++) {
      int c = v * 8 + e;
      float val;
      if (c < 512)       val = bq[c];
      else if (c < 1024) val = bk[c - 512] * 0.125f;
      else if (c < 1536) val = bv[c - 1024];
      else               val = bg[c - 1536];
      bcat[c] = val;
    }
  }
}

// ---------------------------------------------------------------------------
// GEMM: C = A(MxK bf16, row-major) @ W^T (W is NxK bf16 row-major) + bias.
// 128x128 tile, BK=32, 4 waves (2x2 of 64x64), 16x16x32 bf16 MFMA.
// ACT: 0=none, 1=exact gelu. OB: write bf16 out. OF: write fp32 out.
// ---------------------------------------------------------------------------
template <int ACT, int OB, int OF>
__global__ __launch_bounds__(256) void gemm_bf16(
    const u16* __restrict__ A, const u16* __restrict__ W, const float* __restrict__ bias,
    u16* __restrict__ Ob, float* __restrict__ Of, int M, int N, int K) {
  __shared__ __align__(16) u16 As[128 * 32];
  __shared__ __align__(16) u16 Ws[128 * 32];
  const int t = threadIdx.x, l = t & 63;
  const int w = t >> 6, wr = (w >> 1) * 64, wc = (w & 1) * 64;
  const int bm = blockIdx.y * 128, bn = blockIdx.x * 128;
  const int lr = (l >> 4) * 4, lc = l & 15;

  f32x4 acc[4][4] = {};

  const int c0 = t, c1 = t + 256;
  const u16* gA0 = A + (size_t)(bm + (c0 >> 2)) * K + (c0 & 3) * 8;
  const u16* gA1 = A + (size_t)(bm + (c1 >> 2)) * K + (c1 & 3) * 8;
  const u16* gW0 = W + (size_t)(bn + (c0 >> 2)) * K + (c0 & 3) * 8;
  const u16* gW1 = W + (size_t)(bn + (c1 >> 2)) * K + (c1 & 3) * 8;
  u16* sA0 = &As[c0 * 8]; u16* sA1 = &As[c1 * 8];
  u16* sW0 = &Ws[c0 * 8]; u16* sW1 = &Ws[c1 * 8];

  for (int kt = 0; kt < K; kt += 32) {
    gl_lds16(gA0 + kt, sA0);
    gl_lds16(gA1 + kt, sA1);
    gl_lds16(gW0 + kt, sW0);
    gl_lds16(gW1 + kt, sW1);
    __syncthreads();
    bf16x8 af[4], bfr[4];
    #pragma unroll
    for (int i = 0; i < 4; i++)
      af[i] = *(const bf16x8*)&As[(wr + i * 16 + lc) * 32 + ((l >> 4) << 3)];
    #pragma unroll
    for (int i = 0; i < 4; i++)
      bfr[i] = *(const bf16x8*)&Ws[(wc + i * 16 + lc) * 32 + ((l >> 4) << 3)];
    #pragma unroll
    for (int mi = 0; mi < 4; mi++)
      #pragma unroll
      for (int ni = 0; ni < 4; ni++)
        acc[mi][ni] = MFMA16(af[mi], bfr[ni], acc[mi][ni]);
    __syncthreads();
  }

  #pragma unroll
  for (int ni = 0; ni < 4; ni++) {
    int col = bn + wc + ni * 16 + lc;
    float bb = bias[col];
    #pragma unroll
    for (int mi = 0; mi < 4; mi++) {
      #pragma unroll
      for (int r = 0; r < 4; r++) {
        int row = bm + wr + mi * 16 + lr + r;
        float v = acc[mi][ni][r] + bb;
        if (ACT == 1) v = 0.5f * v * (1.0f + erff(v * 0.70710678118f));
        if (OB) Ob[(size_t)row * N + col] = f2bf(v);
        if (OF) Of[(size_t)row * N + col] = v;
      }
    }
  }
}

// ---------------------------------------------------------------------------
// Retention v2: swapped-operand 32x32x16 MFMA, P in registers.
// Block = 512 threads (8 waves), 256 query rows of one (b,h); wave owns 32 rows.
// S^T = mfma32(K, Q)  -> lane col = query i = lane&31 (ai/den per-lane).
// P^T built in-register (cvt_pk_bf16 + shfl_xor 32); O^T = mfma32(V^T, P^T).
// K staged via global_load_lds with XOR-chunk swizzle (rule 21);
// V staged transposed [d][72]. Double-buffered, 1 barrier/tile.
// ---------------------------------------------------------------------------
__global__ __launch_bounds__(512) void retention_v2(
    const u16* __restrict__ qkvg, u16* __restrict__ gated) {
  const int S = 2048, DD = 2048;
  const int bh = blockIdx.y, b = bh >> 3, h = bh & 7;
  const int t = threadIdx.x, l = t & 63, w = t >> 6;
  const int lid = l & 31, hi = l >> 5;
  const int wrow = blockIdx.x * 256 + w * 32;
  const int i_q = wrow + lid;

  // LDS: Ks dbuf [2][64][64] at 0..8191 elems; Vt dbuf [2][64][72] at 8192..17407.
  // Epilogue reuses as Ot: per-wave [32][72] at w*2304.
  __shared__ __align__(16) u16 sm[18432];

  const size_t base = (size_t)b * S * DD + (size_t)h * 64;
  const u16* qp = qkvg + base;
  const u16* kp = qkvg + base + 512;
  const u16* vp = qkvg + base + 1024;
  const u16* gp = qkvg + base + 1536;

  const float gamma = 1.0f - exp2f(-5.0f - (float)h);
  const float l2g = log2f(gamma);          // < 0
  // ai = gamma^i / sqrt(rowsum_i),  rowsum_i = (1 - gamma^(i+1)) * 2^(5+h)
  const float rowsum = (1.0f - exp2f((float)(i_q + 1) * l2g)) * exp2f(5.0f + (float)h);
  const float ai = exp2f((float)i_q * l2g) * rsqrtf(rowsum);
  // bjc[reg] = gamma^-(rr + 8q + 4hi)
  float bjc[16];
  #pragma unroll
  for (int r = 0; r < 16; r++) {
    int joff = (r & 3) + 8 * (r >> 2) + 4 * hi;
    bjc[r] = exp2f(-(float)joff * l2g);
  }
  const float E32 = exp2f(-32.0f * l2g);
  const float E64 = E32 * E32;
  float Ejt = 1.0f;

  // Q as B-operand: lane holds Q[i = lid][k = ks*16 + 8*hi + e]
  bf16x8 qf[4];
  #pragma unroll
  for (int ks = 0; ks < 4; ks++)
    qf[ks] = *(const bf16x8*)(qp + (size_t)i_q * DD + ks * 16 + 8 * hi);

  f32x16 accO0, accO1;
  #pragma unroll
  for (int r = 0; r < 16; r++) { accO0[r] = 0.0f; accO1[r] = 0.0f; }
  float den_acc = 0.0f;

  // staging maps
  const int krow = t >> 3, kcc = t & 7;
  const u16* kg_src = kp + (size_t)krow * DD + ((kcc ^ (krow & 7)) * 8);
  const int vj = t & 63, vd0 = (t >> 6) * 8;
  const u16* vg_src = vp + (size_t)vj * DD + vd0;

  // prologue: stage tile 0 into buf 0
  gl_lds16(kg_src, sm + t * 8);
  {
    u16x8 v0 = *(const u16x8*)vg_src;
    #pragma unroll
    for (int e = 0; e < 8; e++) sm[8192 + (vd0 + e) * 72 + vj] = v0[e];
  }
  __syncthreads();

  int cur = 0;
  for (int jt = 0; jt < S; jt += 64) {
    const int nxt = cur ^ 1;
    const bool pref = (jt + 64 < S);
    u16x8 vreg;
    if (pref) {
      vreg = *(const u16x8*)(vg_src + (size_t)(jt + 64) * DD);
      gl_lds16(kg_src + (size_t)(jt + 64) * DD, sm + nxt * 4096 + t * 8);
    }
    const u16* KsB = sm + cur * 4096;
    const u16* VtB = sm + 8192 + cur * 4608;

    #pragma unroll
    for (int jsub = 0; jsub < 2; jsub++) {
      // QK^T (swapped): S^T[j][i]
      f32x16 s;
      #pragma unroll
      for (int r = 0; r < 16; r++) s[r] = 0.0f;
      #pragma unroll
      for (int ks = 0; ks < 4; ks++) {
        bf16x8 kf = *(const bf16x8*)&KsB[(jsub * 32 + lid) * 64 +
                                         (((2 * ks + hi) ^ (lid & 7)) * 8)];
        s = MFMA32(kf, qf[ks], s);
      }
      // decay bias: + ai * gamma^-j  for j <= i
      {
        const int js = jt + jsub * 32;
        if (js + 31 <= wrow) {            // uniform full
          float coef = ai * Ejt * (jsub ? E32 : 1.0f);
          #pragma unroll
          for (int r = 0; r < 16; r++) s[r] += coef * bjc[r];
        } else if (js <= wrow + 31) {     // boundary: per-element mask
          float coef = ai * Ejt * (jsub ? E32 : 1.0f);
          #pragma unroll
          for (int r = 0; r < 16; r++) {
            int j = js + (r & 3) + 8 * (r >> 2) + 4 * hi;
            s[r] += (j <= i_q) ? coef * bjc[r] : 0.0f;
          }
        }
      }
      // den accumulation (full row incl. non-causal part)
      #pragma unroll
      for (int r = 0; r < 16; r++) den_acc += s[r];
      // cvt to packed bf16 pairs: pk[q*2+x] = pair j = jsub*32 + 8q + 4hi + 2x
      u32 pk[8];
      #pragma unroll
      for (int q = 0; q < 4; q++) {
        pk[q * 2 + 0] = cvt_pk_bf16(s[4 * q + 0], s[4 * q + 1]);
        pk[q * 2 + 1] = cvt_pk_bf16(s[4 * q + 2], s[4 * q + 3]);
      }
      // PV over two 16-j slices (p), P^T B-operand via half-swap exchange
      #pragma unroll
      for (int p = 0; p < 2; p++) {
        u32 own0 = hi ? pk[(2 * p + 1) * 2 + 0] : pk[(2 * p) * 2 + 0];
        u32 own1 = hi ? pk[(2 * p + 1) * 2 + 1] : pk[(2 * p) * 2 + 1];
        u32 snd0 = hi ? pk[(2 * p) * 2 + 0] : pk[(2 * p + 1) * 2 + 0];
        u32 snd1 = hi ? pk[(2 * p) * 2 + 1] : pk[(2 * p + 1) * 2 + 1];
        u32 r0 = __shfl_xor(snd0, 32);
        u32 r1 = __shfl_xor(snd1, 32);
        u32x4 paw;
        paw[0] = hi ? r0 : own0;
        paw[1] = hi ? r1 : own1;
        paw[2] = hi ? own0 : r0;
        paw[3] = hi ? own1 : r1;
        bf16x8 paf = u4_to_bf8(paw);
        const int jsl = jsub * 2 + p;
        bf16x8 vt0 = *(const bf16x8*)&VtB[(lid) * 72 + jsl * 16 + 8 * hi];
        bf16x8 vt1 = *(const bf16x8*)&VtB[(32 + lid) * 72 + jsl * 16 + 8 * hi];
        accO0 = MFMA32(vt0, paf, accO0);
        accO1 = MFMA32(vt1, paf, accO1);
      }
    }

    if (pref) {
      #pragma unroll
      for (int e = 0; e < 8; e++)
        sm[8192 + nxt * 4608 + (vd0 + e) * 72 + vj] = vreg[e];
    }
    Ejt *= E64;
    __syncthreads();
    cur = nxt;
  }

  // ---- epilogue ----
  float den = den_acc + __shfl_xor(den_acc, 32);
  float rden = 1.0f / fmaxf(fabsf(den), 1.0f);
  float o0[16], o1[16];
  float s1 = 0.0f, s2 = 0.0f;
  #pragma unroll
  for (int r = 0; r < 16; r++) {
    o0[r] = accO0[r] * rden; s1 += o0[r]; s2 += o0[r] * o0[r];
    o1[r] = accO1[r] * rden; s1 += o1[r]; s2 += o1[r] * o1[r];
  }
  s1 += __shfl_xor(s1, 32);
  s2 += __shfl_xor(s2, 32);
  float mu = s1 * (1.0f / 64.0f);
  float var = s2 * (1.0f / 64.0f) - mu * mu;
  float rv = rsqrtf(var + 1e-6f);

  // write normalized O to per-wave LDS [32 rows i][72] (d-major)
  u16* Ot = sm + w * 2304;
  #pragma unroll
  for (int r = 0; r < 16; r++) {
    int d = (r & 3) + 8 * (r >> 2) + 4 * hi;
    Ot[lid * 72 + d]      = f2bf((o0[r] - mu) * rv);
    Ot[lid * 72 + 32 + d] = f2bf((o1[r] - mu) * rv);
  }
  // read back coalesced, gate with silu(g), store 128B rows
  {
    const int i2 = l >> 1, half = l & 1;
    const int row = wrow + i2;
    #pragma unroll
    for (int c = 0; c < 4; c++) {
      u16x8 y8 = *(const u16x8*)&Ot[i2 * 72 + half * 32 + c * 8];
      u16x8 g8 = *(const u16x8*)(gp + (size_t)row * DD + half * 32 + c * 8);
      u16x8 o8;
      #pragma unroll
      for (int e = 0; e < 8; e++) {
        float gv = bf2f(g8[e]);
        float sg = gv / (1.0f + __expf(-gv));
        o8[e] = f2bf(bf2f(y8[e]) * sg);
      }
      *(u16x8*)&gated[((size_t)(b * S + row)) * 512 + h * 64 + half * 32 + c * 8] = o8;
    }
  }
}

// ---------------------------------------------------------------------------
// x = LN(A + B) * gam + bet over D=512 (fp32). One wave per row.
// Optionally also writes bf16 copy.
// ---------------------------------------------------------------------------
__global__ __launch_bounds__(256) void add_ln512(
    const float* __restrict__ A, const float* __restrict__ Bv,
    const float* __restrict__ gam, const float* __restrict__ bet, float eps,
    float* __restrict__ Of, u16* __restrict__ Ob) {
  int row = blockIdx.x * 4 + (threadIdx.x >> 6);
  int l = threadIdx.x & 63;
  const float* a = A + (size_t)row * 512 + l * 8;
  const float* c = Bv + (size_t)row * 512 + l * 8;
  f32x4 a0 = *(const f32x4*)a, a1 = *(const f32x4*)(a + 4);
  f32x4 c0 = *(const f32x4*)c, c1 = *(const f32x4*)(c + 4);
  float x[8];
  #pragma unroll
  for (int e = 0; e < 4; e++) { x[e] = a0[e] + c0[e]; x[4 + e] = a1[e] + c1[e]; }
  float s = 0.f, s2 = 0.f;
  #pragma unroll
  for (int e = 0; e < 8; e++) { s += x[e]; s2 += x[e] * x[e]; }
  #pragma unroll
  for (int m = 1; m <= 32; m <<= 1) { s += __shfl_xor(s, m); s2 += __shfl_xor(s2, m); }
  float mu = s * (1.0f / 512.0f);
  float var = s2 * (1.0f / 512.0f) - mu * mu;
  float rinv = rsqrtf(var + eps);
  f32x4 g0 = *(const f32x4*)(gam + l * 8), g1 = *(const f32x4*)(gam + l * 8 + 4);
  f32x4 b0 = *(const f32x4*)(bet + l * 8), b1 = *(const f32x4*)(bet + l * 8 + 4);
  f32x4 y0, y1;
  #pragma unroll
  for (int e = 0; e < 4; e++) {
    y0[e] = (x[e] - mu) * rinv * g0[e] + b0[e];
    y1[e] = (x[4 + e] - mu) * rinv * g1[e] + b1[e];
  }
  float* op = Of + (size_t)row * 512 + l * 8;
  *(f32x4*)op = y0;
  *(f32x4*)(op + 4) = y1;
  if (Ob) {
    u16x8 rb_;
    #pragma unroll
    for (int e = 0; e < 4; e++) { rb_[e] = f2bf(y0[e]); rb_[4 + e] = f2bf(y1[e]); }
    *(u16x8*)(Ob + (size_t)row * 512 + l * 8) = rb_;
  }
}

// ---------------------------------------------------------------------------
// In-place sub-LN over FFN=2048 (bf16), eps 1e-6, affine. One wave per row.
// ---------------------------------------------------------------------------
__global__ __launch_bounds__(256) void subln_ffn(
    u16* __restrict__ hbuf, const float* __restrict__ gam, const float* __restrict__ bet) {
  int row = blockIdx.x * 4 + (threadIdx.x >> 6);
  int l = threadIdx.x & 63;
  u16* p = hbuf + (size_t)row * 2048;
  float x[32];
  #pragma unroll
  for (int cch = 0; cch < 4; cch++) {
    u16x8 v = *(const u16x8*)(p + cch * 512 + l * 8);
    #pragma unroll
    for (int e = 0; e < 8; e++) x[cch * 8 + e] = bf2f(v[e]);
  }
  float s = 0.f, s2 = 0.f;
  #pragma unroll
  for (int e = 0; e < 32; e++) { s += x[e]; s2 += x[e] * x[e]; }
  #pragma unroll
  for (int m = 1; m <= 32; m <<= 1) { s += __shfl_xor(s, m); s2 += __shfl_xor(s2, m); }
  float mu = s * (1.0f / 2048.0f);
  float var = s2 * (1.0f / 2048.0f) - mu * mu;
  float rinv = rsqrtf(var + 1e-6f);
  #pragma unroll
  for (int cch = 0; cch < 4; cch++) {
    int col = cch * 512 + l * 8;
    f32x4 g0 = *(const f32x4*)(gam + col), g1 = *(const f32x4*)(gam + col + 4);
    f32x4 b0 = *(const f32x4*)(bet + col), b1 = *(const f32x4*)(bet + col + 4);
    u16x8 o;
    #pragma unroll
    for (int e = 0; e < 4; e++) {
      o[e]     = f2bf((x[cch * 8 + e]     - mu) * rinv * g0[e] + b0[e]);
      o[4 + e] = f2bf((x[cch * 8 + 4 + e] - mu) * rinv * g1[e] + b1[e]);
    }
    *(u16x8*)(p + col) = o;
  }
}

// ---------------------------------------------------------------------------
extern "C" void kernel_launch(void* const* d_in, const int* in_sizes, int n_in,
                              void* d_out, int out_size, void* d_ws, size_t ws_size,
                              hipStream_t stream) {
  const float* src  = (const float*)d_in[0];
  const float* wq   = (const float*)d_in[3];
  const float* bq   = (const float*)d_in[4];
  const float* wk   = (const float*)d_in[5];
  const float* bk   = (const float*)d_in[6];
  const float* wv   = (const float*)d_in[7];
  const float* bv   = (const float*)d_in[8];
  const float* wg   = (const float*)d_in[9];
  const float* bg   = (const float*)d_in[10];
  const float* wo   = (const float*)d_in[11];
  const float* bo   = (const float*)d_in[12];
  const float* fc1w = (const float*)d_in[13];
  const float* fc1b = (const float*)d_in[14];
  const float* fc2w = (const float*)d_in[15];
  const float* fc2b = (const float*)d_in[16];
  const float* lng  = (const float*)d_in[17];
  const float* lnb  = (const float*)d_in[18];
  const float* n0g  = (const float*)d_in[19];
  const float* n0b  = (const float*)d_in[20];
  const float* n1g  = (const float*)d_in[21];
  const float* n1b  = (const float*)d_in[22];

  if (ws_size < 99098624u) return;  // need ~99.1 MB scratch

  char* ws = (char*)d_ws;
  u16*   src_bf = (u16*)(ws + 0);
  u16*   Wcat   = (u16*)(ws + 8388608);
  u16*   wo_bf  = (u16*)(ws + 10485760);
  u16*   fc1_bf = (u16*)(ws + 11010048);
  u16*   fc2_bf = (u16*)(ws + 13107200);
  float* bcat   = (float*)(ws + 15204352);
  u16*   qkvg   = (u16*)(ws + 15212544);   // 32 MB; reused as h1 after retention
  u16*   gated  = (u16*)(ws + 48766976);
  float* attn   = (float*)(ws + 57155584); // 16 MB; reused as y (fc2 out)
  float* xf     = (float*)(ws + 73932800);
  u16*   xbf    = (u16*)(ws + 90710016);

  // 1. casts / weight concat
  prep_cast<<<3713, 256, 0, stream>>>(src, wq, wk, wv, wg, wo, fc1w, fc2w,
                                      bq, bk, bv, bg,
                                      src_bf, Wcat, wo_bf, fc1_bf, fc2_bf, bcat);
  // 2. QKVG projection: (8192x512) @ (2048x512)^T
  gemm_bf16<0, 1, 0><<<dim3(16, 64), 256, 0, stream>>>(src_bf, Wcat, bcat, qkvg, nullptr,
                                                       8192, 2048, 512);
  // 3. retention + per-head LN + silu gating
  retention_v2<<<dim3(8, 32), 512, 0, stream>>>(qkvg, gated);
  // 4. output projection
  gemm_bf16<0, 0, 1><<<dim3(4, 64), 256, 0, stream>>>(gated, wo_bf, bo, nullptr, attn,
                                                      8192, 512, 512);
  // 5. x = LN(src + attn), n0, eps 1e-5 -> fp32 + bf16
  add_ln512<<<2048, 256, 0, stream>>>(src, attn, n0g, n0b, 1e-5f, xf, xbf);
  // 6. fc1 + exact gelu -> h1 (aliases qkvg)
  gemm_bf16<1, 1, 0><<<dim3(16, 64), 256, 0, stream>>>(xbf, fc1_bf, fc1b, qkvg, nullptr,
                                                       8192, 2048, 512);
  // 7. sub-LN over 2048 (in place)
  subln_ffn<<<2048, 256, 0, stream>>>(qkvg, lng, lnb);
  // 8. fc2 -> y (aliases attn)
  gemm_bf16<0, 0, 1><<<dim3(4, 64), 256, 0, stream>>>(qkvg, fc2_bf, fc2b, nullptr, attn,
                                                      8192, 512, 2048);
  // 9. out = LN(x + y), n1, eps 1e-5 -> d_out (fp32)
  add_ln512<<<2048, 256, 0, stream>>>(xf, attn, n1g, n1b, 1e-5f, (float*)d_out, nullptr);
}

// Round 3
// 217.556 us; speedup vs baseline: 1.2261x; 1.0443x over previous
//
#include <hip/hip_runtime.h>
#include <hip/hip_bf16.h>
#include <math.h>

#define DEV __device__ __forceinline__

typedef __attribute__((ext_vector_type(4))) float f32x4;
typedef __attribute__((ext_vector_type(16))) float f32x16;
typedef __attribute__((ext_vector_type(8))) short bf16x8;     // 8 bf16 in 4 VGPRs (MFMA frag)
typedef __attribute__((ext_vector_type(8))) unsigned short u16x8;
typedef unsigned short u16;
typedef unsigned int u32;
typedef __attribute__((ext_vector_type(4))) u32 u32x4;

DEV u16 f2bf(float f) {
  union { float f; u32 u; } v; v.f = f;
  u32 r = v.u + 0x7fffu + ((v.u >> 16) & 1u);
  return (u16)(r >> 16);
}
DEV float bf2f(u16 h) {
  union { u32 u; float f; } v; v.u = ((u32)h) << 16;
  return v.f;
}

DEV void gl_lds16(const u16* g, u16* s) {
  __builtin_amdgcn_global_load_lds((const __attribute__((address_space(1))) void*)g,
                                   (__attribute__((address_space(3))) void*)s, 16, 0, 0);
}

DEV u32 cvt_pk_bf16(float lo, float hi) {
  u32 r;
  asm("v_cvt_pk_bf16_f32 %0, %1, %2" : "=v"(r) : "v"(lo), "v"(hi));
  return r;
}

DEV bf16x8 u4_to_bf8(u32x4 x) {
  union { u32x4 a; bf16x8 b; } u; u.a = x; return u.b;
}

// raw barrier: no vmcnt drain (unlike __syncthreads), pinned against compiler motion
DEV void barrier_() {
  __builtin_amdgcn_sched_barrier(0);
  asm volatile("" ::: "memory");
  __builtin_amdgcn_s_barrier();
  asm volatile("" ::: "memory");
  __builtin_amdgcn_sched_barrier(0);
}

#define MFMA16(a, b, c) __builtin_amdgcn_mfma_f32_16x16x32_bf16((a), (b), (c), 0, 0, 0)
#define MFMA32(a, b, c) __builtin_amdgcn_mfma_f32_32x32x16_bf16((a), (b), (c), 0, 0, 0)

// ---------------------------------------------------------------------------
// Prep: cast src + weights to bf16; concat wq|wk|wv|wg -> Wcat (k scaled 0.125);
// concat biases bq|bk*0.125|bv|bg -> bcat.
// ---------------------------------------------------------------------------
DEV void cast8(const float* in, u16* out, float s) {
  f32x4 a = *(const f32x4*)in;
  f32x4 b = *(const f32x4*)(in + 4);
  u16x8 r;
  r[0] = f2bf(a[0] * s); r[1] = f2bf(a[1] * s); r[2] = f2bf(a[2] * s); r[3] = f2bf(a[3] * s);
  r[4] = f2bf(b[0] * s); r[5] = f2bf(b[1] * s); r[6] = f2bf(b[2] * s); r[7] = f2bf(b[3] * s);
  *(u16x8*)out = r;
}

__global__ __launch_bounds__(256) void prep_cast(
    const float* __restrict__ src, const float* __restrict__ wq, const float* __restrict__ wk,
    const float* __restrict__ wv, const float* __restrict__ wg, const float* __restrict__ wo,
    const float* __restrict__ fc1, const float* __restrict__ fc2,
    const float* __restrict__ bq, const float* __restrict__ bk,
    const float* __restrict__ bv, const float* __restrict__ bg,
    u16* __restrict__ src_bf, u16* __restrict__ Wcat, u16* __restrict__ wo_bf,
    u16* __restrict__ fc1_bf, u16* __restrict__ fc2_bf, float* __restrict__ bcat) {
  int u = blockIdx.x * 256 + threadIdx.x;
  if (u < 524288) {
    cast8(src + (size_t)u * 8, src_bf + (size_t)u * 8, 1.0f);
  } else if (u < 557056) {
    int v = u - 524288; cast8(wq + (size_t)v * 8, Wcat + (size_t)v * 8, 1.0f);
  } else if (u < 589824) {
    int v = u - 557056; cast8(wk + (size_t)v * 8, Wcat + 262144 + (size_t)v * 8, 0.125f);
  } else if (u < 622592) {
    int v = u - 589824; cast8(wv + (size_t)v * 8, Wcat + 524288 + (size_t)v * 8, 1.0f);
  } else if (u < 655360) {
    int v = u - 622592; cast8(wg + (size_t)v * 8, Wcat + 786432 + (size_t)v * 8, 1.0f);
  } else if (u < 688128) {
    int v = u - 655360; cast8(wo + (size_t)v * 8, wo_bf + (size_t)v * 8, 1.0f);
  } else if (u < 819200) {
    int v = u - 688128; cast8(fc1 + (size_t)v * 8, fc1_bf + (size_t)v * 8, 1.0f);
  } else if (u < 950272) {
    int v = u - 819200; cast8(fc2 + (size_t)v * 8, fc2_bf + (size_t)v * 8, 1.0f);
  } else if (u < 950528) {
    int v = u - 950272;
    #pragma unroll
    for (int e = 0; e < 8; e++) {
      int c = v * 8 + e;
      float val;
      if (c < 512)       val = bq[c];
      else if (c < 1024) val = bk[c - 512] * 0.125f;
      else if (c < 1536) val = bv[c - 1024];
      else               val = bg[c - 1536];
      bcat[c] = val;
    }
  }
}

// ---------------------------------------------------------------------------
// 8-phase 256x256 GEMM (T1+T2+T3+T4+T5): C = A @ W^T + bias, bf16 out.
// 512 thr (8 waves, 2Mx4N), BK=64 as two K-halves; LDS 128 KiB:
// 2 slots x regions [Bk0|Ak0|Bk1|Ak1] each [256 rows][32 k] bf16, chunk-swizzled
// chunk' = chunk ^ ((row>>1)&3) (conflict-free 16x16x32 frag reads; rule 21:
// inverse swizzle applied on the global source of global_load_lds).
// Per tile: 4 phases {dsread frags | stage 1 half | bar | lgkm0 | 16 MFMA | bar},
// stage lead = 7 halves, vmcnt(6) once per tile (vmcnt(0) last tile).
// ---------------------------------------------------------------------------
template <int ACT>
__global__ __launch_bounds__(512, 2) void gemm256_8ph(
    const u16* __restrict__ A, const u16* __restrict__ W, const float* __restrict__ bias,
    u16* __restrict__ Ob, int N, int K) {
  __shared__ __align__(16) u16 sm[65536];   // 128 KiB
  const int NT = K >> 6;
  const int tid = threadIdx.x, l = tid & 63, w = tid >> 6;
  const int wm = w >> 2, wn = w & 3;
  const int orig = blockIdx.x;
  const int sid = (orig & 7) * 32 + (orig >> 3);        // XCD-contiguous M-stripes
  const int bm = (sid >> 3) * 256, bn = (sid & 7) * 256;
  const int lc = l & 15, lch = l >> 4;

  // staging source constants (pre-swizzled global source)
  const int rT = tid >> 2;                              // region row 0..127
  const int colu = ((tid & 3) ^ ((rT >> 1) & 3)) * 8;   // source chunk (u16)
  const u16* stA = A + (size_t)(bm + rT) * K + colu;
  const u16* stB = W + (size_t)(bn + rT) * K + colu;
  const size_t rowStep = (size_t)128 * K;

  // frag read offsets (u16): region [256][32], swizzled chunk position
  const int pos = lch ^ ((lc >> 1) & 3);
  const int aoff = (wm * 128 + lc) * 32 + pos * 8;
  const int boff = (wn * 64 + lc) * 32 + pos * 8;

  f32x4 acc[8][4] = {};
  bf16x8 bfr[4];

#define STG(Ts, j, isA, kh)                                            \
  {                                                                    \
    u16* dst = sm + ((Ts) & 1) * 32768 + (j) * 8192 + tid * 8;         \
    const u16* s0 = ((isA) ? stA : stB) + (Ts) * 64 + (kh) * 32;       \
    gl_lds16(s0, dst);                                                 \
    gl_lds16(s0 + rowStep, dst + 4096);                                \
  }

  // prologue: stage halves h0..h6 (tile0 full + tile1 Bk0,Ak0,Bk1)
  STG(0, 0, 0, 0) STG(0, 1, 1, 0) STG(0, 2, 0, 1) STG(0, 3, 1, 1)
  STG(1, 0, 0, 0) STG(1, 1, 1, 0) STG(1, 2, 0, 1)

  for (int t = 0; t < NT; ++t) {
    const int slot = t & 1;
    const u16* S = sm + slot * 32768;
#define PHASE(q)                                                               \
    {                                                                          \
      constexpr int kh = (q) >> 1;                                             \
      constexpr int mh = (q) & 1;                                              \
      const u16* Ar = S + (1 + 2 * kh) * 8192;                                 \
      const u16* Br = S + (2 * kh) * 8192;                                     \
      if ((q) == 0) {                                                          \
        if (t == NT - 1) { asm volatile("s_waitcnt vmcnt(0)" ::: "memory"); }  \
        else             { asm volatile("s_waitcnt vmcnt(6)" ::: "memory"); }  \
      }                                                                        \
      barrier_();                                                              \
      bf16x8 afr[4];                                                           \
      _Pragma("unroll")                                                        \
      for (int mi = 0; mi < 4; mi++)                                           \
        afr[mi] = *(const bf16x8*)&Ar[aoff + (mh * 4 + mi) * 512];             \
      if (!mh) {                                                               \
        _Pragma("unroll")                                                      \
        for (int ni = 0; ni < 4; ni++)                                         \
          bfr[ni] = *(const bf16x8*)&Br[boff + ni * 512];                      \
      }                                                                        \
      {                                                                        \
        constexpr int jj = ((q) + 3) & 3;                                      \
        const int Ts = t + ((q) == 0 ? 1 : 2);                                 \
        if (Ts < NT) STG(Ts, jj, (jj & 1), (jj >> 1))                          \
      }                                                                        \
      barrier_();                                                              \
      asm volatile("s_waitcnt lgkmcnt(0)" ::: "memory");                       \
      __builtin_amdgcn_sched_barrier(0);                                       \
      __builtin_amdgcn_s_setprio(1);                                           \
      _Pragma("unroll")                                                        \
      for (int mi = 0; mi < 4; mi++) {                                         \
        _Pragma("unroll")                                                      \
        for (int ni = 0; ni < 4; ni++)                                         \
          acc[mh * 4 + mi][ni] = MFMA16(afr[mi], bfr[ni], acc[mh * 4 + mi][ni]); \
      }                                                                        \
      __builtin_amdgcn_s_setprio(0);                                           \
    }
    PHASE(0) PHASE(1) PHASE(2) PHASE(3)
#undef PHASE
  }
#undef STG

  // epilogue: bias (+gelu) -> bf16
  #pragma unroll
  for (int nf = 0; nf < 4; nf++) {
    int col = bn + wn * 64 + nf * 16 + lc;
    float bb = bias[col];
    #pragma unroll
    for (int mf = 0; mf < 8; mf++) {
      #pragma unroll
      for (int r = 0; r < 4; r++) {
        int row = bm + wm * 128 + mf * 16 + lch * 4 + r;
        float v = acc[mf][nf][r] + bb;
        if (ACT == 1) v = 0.5f * v * (1.0f + erff(v * 0.70710678118f));
        Ob[(size_t)row * N + col] = f2bf(v);
      }
    }
  }
}

// ---------------------------------------------------------------------------
// GEMM (2-phase 128x128): C = A @ W^T + bias. Used for N=512 GEMMs (wo, fc2).
// ---------------------------------------------------------------------------
template <int ACT, int OB, int OF>
__global__ __launch_bounds__(256) void gemm_bf16(
    const u16* __restrict__ A, const u16* __restrict__ W, const float* __restrict__ bias,
    u16* __restrict__ Ob, float* __restrict__ Of, int M, int N, int K) {
  __shared__ __align__(16) u16 As[128 * 32];
  __shared__ __align__(16) u16 Ws[128 * 32];
  const int t = threadIdx.x, l = t & 63;
  const int w = t >> 6, wr = (w >> 1) * 64, wc = (w & 1) * 64;
  const int bm = blockIdx.y * 128, bn = blockIdx.x * 128;
  const int lr = (l >> 4) * 4, lc = l & 15;

  f32x4 acc[4][4] = {};

  const int c0 = t, c1 = t + 256;
  const u16* gA0 = A + (size_t)(bm + (c0 >> 2)) * K + (c0 & 3) * 8;
  const u16* gA1 = A + (size_t)(bm + (c1 >> 2)) * K + (c1 & 3) * 8;
  const u16* gW0 = W + (size_t)(bn + (c0 >> 2)) * K + (c0 & 3) * 8;
  const u16* gW1 = W + (size_t)(bn + (c1 >> 2)) * K + (c1 & 3) * 8;
  u16* sA0 = &As[c0 * 8]; u16* sA1 = &As[c1 * 8];
  u16* sW0 = &Ws[c0 * 8]; u16* sW1 = &Ws[c1 * 8];

  for (int kt = 0; kt < K; kt += 32) {
    gl_lds16(gA0 + kt, sA0);
    gl_lds16(gA1 + kt, sA1);
    gl_lds16(gW0 + kt, sW0);
    gl_lds16(gW1 + kt, sW1);
    __syncthreads();
    bf16x8 af[4], bfr[4];
    #pragma unroll
    for (int i = 0; i < 4; i++)
      af[i] = *(const bf16x8*)&As[(wr + i * 16 + lc) * 32 + ((l >> 4) << 3)];
    #pragma unroll
    for (int i = 0; i < 4; i++)
      bfr[i] = *(const bf16x8*)&Ws[(wc + i * 16 + lc) * 32 + ((l >> 4) << 3)];
    #pragma unroll
    for (int mi = 0; mi < 4; mi++)
      #pragma unroll
      for (int ni = 0; ni < 4; ni++)
        acc[mi][ni] = MFMA16(af[mi], bfr[ni], acc[mi][ni]);
    __syncthreads();
  }

  #pragma unroll
  for (int ni = 0; ni < 4; ni++) {
    int col = bn + wc + ni * 16 + lc;
    float bb = bias[col];
    #pragma unroll
    for (int mi = 0; mi < 4; mi++) {
      #pragma unroll
      for (int r = 0; r < 4; r++) {
        int row = bm + wr + mi * 16 + lr + r;
        float v = acc[mi][ni][r] + bb;
        if (ACT == 1) v = 0.5f * v * (1.0f + erff(v * 0.70710678118f));
        if (OB) Ob[(size_t)row * N + col] = f2bf(v);
        if (OF) Of[(size_t)row * N + col] = v;
      }
    }
  }
}

// ---------------------------------------------------------------------------
// Retention v2: swapped-operand 32x32x16 MFMA, P in registers.
// ---------------------------------------------------------------------------
__global__ __launch_bounds__(512) void retention_v2(
    const u16* __restrict__ qkvg, u16* __restrict__ gated) {
  const int S = 2048, DD = 2048;
  const int bh = blockIdx.y, b = bh >> 3, h = bh & 7;
  const int t = threadIdx.x, l = t & 63, w = t >> 6;
  const int lid = l & 31, hi = l >> 5;
  const int wrow = blockIdx.x * 256 + w * 32;
  const int i_q = wrow + lid;

  __shared__ __align__(16) u16 sm[18432];

  const size_t base = (size_t)b * S * DD + (size_t)h * 64;
  const u16* qp = qkvg + base;
  const u16* kp = qkvg + base + 512;
  const u16* vp = qkvg + base + 1024;
  const u16* gp = qkvg + base + 1536;

  const float gamma = 1.0f - exp2f(-5.0f - (float)h);
  const float l2g = log2f(gamma);          // < 0
  const float rowsum = (1.0f - exp2f((float)(i_q + 1) * l2g)) * exp2f(5.0f + (float)h);
  const float ai = exp2f((float)i_q * l2g) * rsqrtf(rowsum);
  float bjc[16];
  #pragma unroll
  for (int r = 0; r < 16; r++) {
    int joff = (r & 3) + 8 * (r >> 2) + 4 * hi;
    bjc[r] = exp2f(-(float)joff * l2g);
  }
  const float E32 = exp2f(-32.0f * l2g);
  const float E64 = E32 * E32;
  float Ejt = 1.0f;

  bf16x8 qf[4];
  #pragma unroll
  for (int ks = 0; ks < 4; ks++)
    qf[ks] = *(const bf16x8*)(qp + (size_t)i_q * DD + ks * 16 + 8 * hi);

  f32x16 accO0, accO1;
  #pragma unroll
  for (int r = 0; r < 16; r++) { accO0[r] = 0.0f; accO1[r] = 0.0f; }
  float den_acc = 0.0f;

  const int krow = t >> 3, kcc = t & 7;
  const u16* kg_src = kp + (size_t)krow * DD + ((kcc ^ (krow & 7)) * 8);
  const int vj = t & 63, vd0 = (t >> 6) * 8;
  const u16* vg_src = vp + (size_t)vj * DD + vd0;

  gl_lds16(kg_src, sm + t * 8);
  {
    u16x8 v0 = *(const u16x8*)vg_src;
    #pragma unroll
    for (int e = 0; e < 8; e++) sm[8192 + (vd0 + e) * 72 + vj] = v0[e];
  }
  __syncthreads();

  int cur = 0;
  for (int jt = 0; jt < S; jt += 64) {
    const int nxt = cur ^ 1;
    const bool pref = (jt + 64 < S);
    u16x8 vreg;
    if (pref) {
      vreg = *(const u16x8*)(vg_src + (size_t)(jt + 64) * DD);
      gl_lds16(kg_src + (size_t)(jt + 64) * DD, sm + nxt * 4096 + t * 8);
    }
    const u16* KsB = sm + cur * 4096;
    const u16* VtB = sm + 8192 + cur * 4608;

    #pragma unroll
    for (int jsub = 0; jsub < 2; jsub++) {
      f32x16 s;
      #pragma unroll
      for (int r = 0; r < 16; r++) s[r] = 0.0f;
      #pragma unroll
      for (int ks = 0; ks < 4; ks++) {
        bf16x8 kf = *(const bf16x8*)&KsB[(jsub * 32 + lid) * 64 +
                                         (((2 * ks + hi) ^ (lid & 7)) * 8)];
        s = MFMA32(kf, qf[ks], s);
      }
      {
        const int js = jt + jsub * 32;
        if (js + 31 <= wrow) {
          float coef = ai * Ejt * (jsub ? E32 : 1.0f);
          #pragma unroll
          for (int r = 0; r < 16; r++) s[r] += coef * bjc[r];
        } else if (js <= wrow + 31) {
          float coef = ai * Ejt * (jsub ? E32 : 1.0f);
          #pragma unroll
          for (int r = 0; r < 16; r++) {
            int j = js + (r & 3) + 8 * (r >> 2) + 4 * hi;
            s[r] += (j <= i_q) ? coef * bjc[r] : 0.0f;
          }
        }
      }
      #pragma unroll
      for (int r = 0; r < 16; r++) den_acc += s[r];
      u32 pk[8];
      #pragma unroll
      for (int q = 0; q < 4; q++) {
        pk[q * 2 + 0] = cvt_pk_bf16(s[4 * q + 0], s[4 * q + 1]);
        pk[q * 2 + 1] = cvt_pk_bf16(s[4 * q + 2], s[4 * q + 3]);
      }
      #pragma unroll
      for (int p = 0; p < 2; p++) {
        u32 own0 = hi ? pk[(2 * p + 1) * 2 + 0] : pk[(2 * p) * 2 + 0];
        u32 own1 = hi ? pk[(2 * p + 1) * 2 + 1] : pk[(2 * p) * 2 + 1];
        u32 snd0 = hi ? pk[(2 * p) * 2 + 0] : pk[(2 * p + 1) * 2 + 0];
        u32 snd1 = hi ? pk[(2 * p) * 2 + 1] : pk[(2 * p + 1) * 2 + 1];
        u32 r0 = __shfl_xor(snd0, 32);
        u32 r1 = __shfl_xor(snd1, 32);
        u32x4 paw;
        paw[0] = hi ? r0 : own0;
        paw[1] = hi ? r1 : own1;
        paw[2] = hi ? own0 : r0;
        paw[3] = hi ? own1 : r1;
        bf16x8 paf = u4_to_bf8(paw);
        const int jsl = jsub * 2 + p;
        bf16x8 vt0 = *(const bf16x8*)&VtB[(lid) * 72 + jsl * 16 + 8 * hi];
        bf16x8 vt1 = *(const bf16x8*)&VtB[(32 + lid) * 72 + jsl * 16 + 8 * hi];
        accO0 = MFMA32(vt0, paf, accO0);
        accO1 = MFMA32(vt1, paf, accO1);
      }
    }

    if (pref) {
      #pragma unroll
      for (int e = 0; e < 8; e++)
        sm[8192 + nxt * 4608 + (vd0 + e) * 72 + vj] = vreg[e];
    }
    Ejt *= E64;
    __syncthreads();
    cur = nxt;
  }

  float den = den_acc + __shfl_xor(den_acc, 32);
  float rden = 1.0f / fmaxf(fabsf(den), 1.0f);
  float o0[16], o1[16];
  float s1 = 0.0f, s2 = 0.0f;
  #pragma unroll
  for (int r = 0; r < 16; r++) {
    o0[r] = accO0[r] * rden; s1 += o0[r]; s2 += o0[r] * o0[r];
    o1[r] = accO1[r] * rden; s1 += o1[r]; s2 += o1[r] * o1[r];
  }
  s1 += __shfl_xor(s1, 32);
  s2 += __shfl_xor(s2, 32);
  float mu = s1 * (1.0f / 64.0f);
  float var = s2 * (1.0f / 64.0f) - mu * mu;
  float rv = rsqrtf(var + 1e-6f);

  u16* Ot = sm + w * 2304;
  #pragma unroll
  for (int r = 0; r < 16; r++) {
    int d = (r & 3) + 8 * (r >> 2) + 4 * hi;
    Ot[lid * 72 + d]      = f2bf((o0[r] - mu) * rv);
    Ot[lid * 72 + 32 + d] = f2bf((o1[r] - mu) * rv);
  }
  {
    const int i2 = l >> 1, half = l & 1;
    const int row = wrow + i2;
    #pragma unroll
    for (int c = 0; c < 4; c++) {
      u16x8 y8 = *(const u16x8*)&Ot[i2 * 72 + half * 32 + c * 8];
      u16x8 g8 = *(const u16x8*)(gp + (size_t)row * DD + half * 32 + c * 8);
      u16x8 o8;
      #pragma unroll
      for (int e = 0; e < 8; e++) {
        float gv = bf2f(g8[e]);
        float sg = gv / (1.0f + __expf(-gv));
        o8[e] = f2bf(bf2f(y8[e]) * sg);
      }
      *(u16x8*)&gated[((size_t)(b * S + row)) * 512 + h * 64 + half * 32 + c * 8] = o8;
    }
  }
}

// ---------------------------------------------------------------------------
// x = LN(A + B) * gam + bet over D=512 (fp32). One wave per row.
// ---------------------------------------------------------------------------
__global__ __launch_bounds__(256) void add_ln512(
    const float* __restrict__ A, const float* __restrict__ Bv,
    const float* __restrict__ gam, const float* __restrict__ bet, float eps,
    float* __restrict__ Of, u16* __restrict__ Ob) {
  int row = blockIdx.x * 4 + (threadIdx.x >> 6);
  int l = threadIdx.x & 63;
  const float* a = A + (size_t)row * 512 + l * 8;
  const float* c = Bv + (size_t)row * 512 + l * 8;
  f32x4 a0 = *(const f32x4*)a, a1 = *(const f32x4*)(a + 4);
  f32x4 c0 = *(const f32x4*)c, c1 = *(const f32x4*)(c + 4);
  float x[8];
  #pragma unroll
  for (int e = 0; e < 4; e++) { x[e] = a0[e] + c0[e]; x[4 + e] = a1[e] + c1[e]; }
  float s = 0.f, s2 = 0.f;
  #pragma unroll
  for (int e = 0; e < 8; e++) { s += x[e]; s2 += x[e] * x[e]; }
  #pragma unroll
  for (int m = 1; m <= 32; m <<= 1) { s += __shfl_xor(s, m); s2 += __shfl_xor(s2, m); }
  float mu = s * (1.0f / 512.0f);
  float var = s2 * (1.0f / 512.0f) - mu * mu;
  float rinv = rsqrtf(var + eps);
  f32x4 g0 = *(const f32x4*)(gam + l * 8), g1 = *(const f32x4*)(gam + l * 8 + 4);
  f32x4 b0 = *(const f32x4*)(bet + l * 8), b1 = *(const f32x4*)(bet + l * 8 + 4);
  f32x4 y0, y1;
  #pragma unroll
  for (int e = 0; e < 4; e++) {
    y0[e] = (x[e] - mu) * rinv * g0[e] + b0[e];
    y1[e] = (x[4 + e] - mu) * rinv * g1[e] + b1[e];
  }
  float* op = Of + (size_t)row * 512 + l * 8;
  *(f32x4*)op = y0;
  *(f32x4*)(op + 4) = y1;
  if (Ob) {
    u16x8 rb_;
    #pragma unroll
    for (int e = 0; e < 4; e++) { rb_[e] = f2bf(y0[e]); rb_[4 + e] = f2bf(y1[e]); }
    *(u16x8*)(Ob + (size_t)row * 512 + l * 8) = rb_;
  }
}

// ---------------------------------------------------------------------------
// In-place sub-LN over FFN=2048 (bf16), eps 1e-6, affine. One wave per row.
// ---------------------------------------------------------------------------
__global__ __launch_bounds__(256) void subln_ffn(
    u16* __restrict__ hbuf, const float* __restrict__ gam, const float* __restrict__ bet) {
  int row = blockIdx.x * 4 + (threadIdx.x >> 6);
  int l = threadIdx.x & 63;
  u16* p = hbuf + (size_t)row * 2048;
  float x[32];
  #pragma unroll
  for (int cch = 0; cch < 4; cch++) {
    u16x8 v = *(const u16x8*)(p + cch * 512 + l * 8);
    #pragma unroll
    for (int e = 0; e < 8; e++) x[cch * 8 + e] = bf2f(v[e]);
  }
  float s = 0.f, s2 = 0.f;
  #pragma unroll
  for (int e = 0; e < 32; e++) { s += x[e]; s2 += x[e] * x[e]; }
  #pragma unroll
  for (int m = 1; m <= 32; m <<= 1) { s += __shfl_xor(s, m); s2 += __shfl_xor(s2, m); }
  float mu = s * (1.0f / 2048.0f);
  float var = s2 * (1.0f / 2048.0f) - mu * mu;
  float rinv = rsqrtf(var + 1e-6f);
  #pragma unroll
  for (int cch = 0; cch < 4; cch++) {
    int col = cch * 512 + l * 8;
    f32x4 g0 = *(const f32x4*)(gam + col), g1 = *(const f32x4*)(gam + col + 4);
    f32x4 b0 = *(const f32x4*)(bet + col), b1 = *(const f32x4*)(bet + col + 4);
    u16x8 o;
    #pragma unroll
    for (int e = 0; e < 4; e++) {
      o[e]     = f2bf((x[cch * 8 + e]     - mu) * rinv * g0[e] + b0[e]);
      o[4 + e] = f2bf((x[cch * 8 + 4 + e] - mu) * rinv * g1[e] + b1[e]);
    }
    *(u16x8*)(p + col) = o;
  }
}

// ---------------------------------------------------------------------------
extern "C" void kernel_launch(void* const* d_in, const int* in_sizes, int n_in,
                              void* d_out, int out_size, void* d_ws, size_t ws_size,
                              hipStream_t stream) {
  const float* src  = (const float*)d_in[0];
  const float* wq   = (const float*)d_in[3];
  const float* bq   = (const float*)d_in[4];
  const float* wk   = (const float*)d_in[5];
  const float* bk   = (const float*)d_in[6];
  const float* wv   = (const float*)d_in[7];
  const float* bv   = (const float*)d_in[8];
  const float* wg   = (const float*)d_in[9];
  const float* bg   = (const float*)d_in[10];
  const float* wo   = (const float*)d_in[11];
  const float* bo   = (const float*)d_in[12];
  const float* fc1w = (const float*)d_in[13];
  const float* fc1b = (const float*)d_in[14];
  const float* fc2w = (const float*)d_in[15];
  const float* fc2b = (const float*)d_in[16];
  const float* lng  = (const float*)d_in[17];
  const float* lnb  = (const float*)d_in[18];
  const float* n0g  = (const float*)d_in[19];
  const float* n0b  = (const float*)d_in[20];
  const float* n1g  = (const float*)d_in[21];
  const float* n1b  = (const float*)d_in[22];

  if (ws_size < 99098624u) return;  // need ~99.1 MB scratch

  char* ws = (char*)d_ws;
  u16*   src_bf = (u16*)(ws + 0);
  u16*   Wcat   = (u16*)(ws + 8388608);
  u16*   wo_bf  = (u16*)(ws + 10485760);
  u16*   fc1_bf = (u16*)(ws + 11010048);
  u16*   fc2_bf = (u16*)(ws + 13107200);
  float* bcat   = (float*)(ws + 15204352);
  u16*   qkvg   = (u16*)(ws + 15212544);   // 32 MB; reused as h1 after retention
  u16*   gated  = (u16*)(ws + 48766976);
  float* attn   = (float*)(ws + 57155584); // 16 MB; reused as y (fc2 out)
  float* xf     = (float*)(ws + 73932800);
  u16*   xbf    = (u16*)(ws + 90710016);

  // 1. casts / weight concat
  prep_cast<<<3713, 256, 0, stream>>>(src, wq, wk, wv, wg, wo, fc1w, fc2w,
                                      bq, bk, bv, bg,
                                      src_bf, Wcat, wo_bf, fc1_bf, fc2_bf, bcat);
  // 2. QKVG projection: (8192x512) @ (2048x512)^T  [8-phase 256^2]
  gemm256_8ph<0><<<256, 512, 0, stream>>>(src_bf, Wcat, bcat, qkvg, 2048, 512);
  // 3. retention + per-head LN + silu gating
  retention_v2<<<dim3(8, 32), 512, 0, stream>>>(qkvg, gated);
  // 4. output projection (N=512)
  gemm_bf16<0, 0, 1><<<dim3(4, 64), 256, 0, stream>>>(gated, wo_bf, bo, nullptr, attn,
                                                      8192, 512, 512);
  // 5. x = LN(src + attn), n0, eps 1e-5 -> fp32 + bf16
  add_ln512<<<2048, 256, 0, stream>>>(src, attn, n0g, n0b, 1e-5f, xf, xbf);
  // 6. fc1 + exact gelu -> h1 (aliases qkvg)  [8-phase 256^2]
  gemm256_8ph<1><<<256, 512, 0, stream>>>(xbf, fc1_bf, fc1b, qkvg, 2048, 512);
  // 7. sub-LN over 2048 (in place)
  subln_ffn<<<2048, 256, 0, stream>>>(qkvg, lng, lnb);
  // 8. fc2 -> y (aliases attn)
  gemm_bf16<0, 0, 1><<<dim3(4, 64), 256, 0, stream>>>(qkvg, fc2_bf, fc2b, nullptr, attn,
                                                      8192, 512, 2048);
  // 9. out = LN(x + y), n1, eps 1e-5 -> d_out (fp32)
  add_ln512<<<2048, 256, 0, stream>>>(xf, attn, n1g, n1b, 1e-5f, (float*)d_out, nullptr);
}

// Round 4
// 190.214 us; speedup vs baseline: 1.4023x; 1.1437x over previous
//
#include <hip/hip_runtime.h>
#include <hip/hip_bf16.h>
#include <math.h>

#define DEV __device__ __forceinline__

typedef __attribute__((ext_vector_type(4))) float f32x4;
typedef __attribute__((ext_vector_type(16))) float f32x16;
typedef __attribute__((ext_vector_type(8))) short bf16x8;     // 8 bf16 in 4 VGPRs (MFMA frag)
typedef __attribute__((ext_vector_type(8))) unsigned short u16x8;
typedef unsigned short u16;
typedef unsigned int u32;
typedef __attribute__((ext_vector_type(4))) u32 u32x4;

DEV u16 f2bf(float f) {
  union { float f; u32 u; } v; v.f = f;
  u32 r = v.u + 0x7fffu + ((v.u >> 16) & 1u);
  return (u16)(r >> 16);
}
DEV float bf2f(u16 h) {
  union { u32 u; float f; } v; v.u = ((u32)h) << 16;
  return v.f;
}

DEV void gl_lds16(const u16* g, u16* s) {
  __builtin_amdgcn_global_load_lds((const __attribute__((address_space(1))) void*)g,
                                   (__attribute__((address_space(3))) void*)s, 16, 0, 0);
}

DEV u32 cvt_pk_bf16(float lo, float hi) {
  u32 r;
  asm("v_cvt_pk_bf16_f32 %0, %1, %2" : "=v"(r) : "v"(lo), "v"(hi));
  return r;
}

DEV bf16x8 u4_to_bf8(u32x4 x) {
  union { u32x4 a; bf16x8 b; } u; u.a = x; return u.b;
}

#define MFMA16(a, b, c) __builtin_amdgcn_mfma_f32_16x16x32_bf16((a), (b), (c), 0, 0, 0)
#define MFMA32(a, b, c) __builtin_amdgcn_mfma_f32_32x32x16_bf16((a), (b), (c), 0, 0, 0)

// ---------------------------------------------------------------------------
// Prep: cast src + weights to bf16; concat wq|wk|wv|wg -> Wcat (k scaled 0.125);
// concat biases bq|bk*0.125|bv|bg -> bcat.
// ---------------------------------------------------------------------------
DEV void cast8(const float* in, u16* out, float s) {
  f32x4 a = *(const f32x4*)in;
  f32x4 b = *(const f32x4*)(in + 4);
  u16x8 r;
  r[0] = f2bf(a[0] * s); r[1] = f2bf(a[1] * s); r[2] = f2bf(a[2] * s); r[3] = f2bf(a[3] * s);
  r[4] = f2bf(b[0] * s); r[5] = f2bf(b[1] * s); r[6] = f2bf(b[2] * s); r[7] = f2bf(b[3] * s);
  *(u16x8*)out = r;
}

__global__ __launch_bounds__(256) void prep_cast(
    const float* __restrict__ src, const float* __restrict__ wq, const float* __restrict__ wk,
    const float* __restrict__ wv, const float* __restrict__ wg, const float* __restrict__ wo,
    const float* __restrict__ fc1, const float* __restrict__ fc2,
    const float* __restrict__ bq, const float* __restrict__ bk,
    const float* __restrict__ bv, const float* __restrict__ bg,
    u16* __restrict__ src_bf, u16* __restrict__ Wcat, u16* __restrict__ wo_bf,
    u16* __restrict__ fc1_bf, u16* __restrict__ fc2_bf, float* __restrict__ bcat) {
  int u = blockIdx.x * 256 + threadIdx.x;
  if (u < 524288) {
    cast8(src + (size_t)u * 8, src_bf + (size_t)u * 8, 1.0f);
  } else if (u < 557056) {
    int v = u - 524288; cast8(wq + (size_t)v * 8, Wcat + (size_t)v * 8, 1.0f);
  } else if (u < 589824) {
    int v = u - 557056; cast8(wk + (size_t)v * 8, Wcat + 262144 + (size_t)v * 8, 0.125f);
  } else if (u < 622592) {
    int v = u - 589824; cast8(wv + (size_t)v * 8, Wcat + 524288 + (size_t)v * 8, 1.0f);
  } else if (u < 655360) {
    int v = u - 622592; cast8(wg + (size_t)v * 8, Wcat + 786432 + (size_t)v * 8, 1.0f);
  } else if (u < 688128) {
    int v = u - 655360; cast8(wo + (size_t)v * 8, wo_bf + (size_t)v * 8, 1.0f);
  } else if (u < 819200) {
    int v = u - 688128; cast8(fc1 + (size_t)v * 8, fc1_bf + (size_t)v * 8, 1.0f);
  } else if (u < 950272) {
    int v = u - 819200; cast8(fc2 + (size_t)v * 8, fc2_bf + (size_t)v * 8, 1.0f);
  } else if (u < 950528) {
    int v = u - 950272;
    #pragma unroll
    for (int e = 0; e < 8; e++) {
      int c = v * 8 + e;
      float val;
      if (c < 512)       val = bq[c];
      else if (c < 1024) val = bk[c - 512] * 0.125f;
      else if (c < 1536) val = bv[c - 1024];
      else               val = bg[c - 1536];
      bcat[c] = val;
    }
  }
}

// ---------------------------------------------------------------------------
// gemm_v3: C = A(MxK) @ W^T (W NxK) + bias, bf16 out. Retention-style schedule:
// 128x128 tile, BK=64, 4 waves (2x2, 64x64 each), double-buffered 64KB LDS,
// ONE __syncthreads per K-iter, prefetch issued before the compute window.
// LDS chunk-swizzle c' = c ^ (row&7) (16B chunks), applied on the global
// source of global_load_lds (rule 21) and on the ds_read address -> 2-way max.
// Epilogue: acc -> swizzled LDS tile -> coalesced 16B/lane stores.
// ---------------------------------------------------------------------------
template <int ACT>
__global__ __launch_bounds__(256) void gemm_v3(
    const u16* __restrict__ A, const u16* __restrict__ W, const float* __restrict__ bias,
    u16* __restrict__ Ob, int N, int K, int TN) {
  __shared__ __align__(16) u16 sm[2][16384];   // [buf][A:0..8191 | B:8192..16383]
  const int t = threadIdx.x, l = t & 63;
  const int w = t >> 6, wr = (w >> 1) * 64, wc = (w & 1) * 64;
  const int lc = l & 15, lch = l >> 4;
  const int NT = K >> 6;

  // XCD-bijective chunked swizzle (grid % 8 == 0 for all our launches)
  const int orig = blockIdx.x;
  const int cpx = gridDim.x >> 3;
  const int sid = (orig & 7) * cpx + (orig >> 3);
  const int bm = (sid / TN) * 128, bn = (sid % TN) * 128;

  // staging map: thread covers (srow, chunk sc8) of each 32-row group
  const int srow = t >> 3, sc8 = t & 7;
  const u16* stA = A + (size_t)(bm + srow) * K + ((sc8 ^ (srow & 7)) * 8);
  const u16* stB = W + (size_t)(bn + srow) * K + ((sc8 ^ (srow & 7)) * 8);

#define STAGE(bidx, kt)                                                        \
  {                                                                            \
    u16* d = (u16*)sm[bidx] + t * 8;                                           \
    _Pragma("unroll")                                                          \
    for (int j = 0; j < 4; j++)                                                \
      gl_lds16(stA + (size_t)j * 32 * K + (kt), d + j * 2048);                 \
    _Pragma("unroll")                                                          \
    for (int j = 0; j < 4; j++)                                                \
      gl_lds16(stB + (size_t)j * 32 * K + (kt), d + 8192 + j * 2048);          \
  }

  f32x4 acc[4][4] = {};

  STAGE(0, 0)
  __syncthreads();

  for (int tt = 0; tt < NT; ++tt) {
    if (tt + 1 < NT) STAGE((tt + 1) & 1, (tt + 1) * 64)
    const u16* bufp = sm[tt & 1];
    bf16x8 af[4][2], bfv[4][2];
    #pragma unroll
    for (int mi = 0; mi < 4; mi++) {
      const int row = wr + mi * 16 + lc;
      #pragma unroll
      for (int ks = 0; ks < 2; ks++) {
        const int ch = ks * 4 + lch;
        af[mi][ks] = *(const bf16x8*)&bufp[row * 64 + ((ch ^ (row & 7)) * 8)];
      }
    }
    #pragma unroll
    for (int ni = 0; ni < 4; ni++) {
      const int row = wc + ni * 16 + lc;
      #pragma unroll
      for (int ks = 0; ks < 2; ks++) {
        const int ch = ks * 4 + lch;
        bfv[ni][ks] = *(const bf16x8*)&bufp[8192 + row * 64 + ((ch ^ (row & 7)) * 8)];
      }
    }
    #pragma unroll
    for (int ks = 0; ks < 2; ks++)
      #pragma unroll
      for (int mi = 0; mi < 4; mi++)
        #pragma unroll
        for (int ni = 0; ni < 4; ni++)
          acc[mi][ni] = MFMA16(af[mi][ks], bfv[ni][ks], acc[mi][ni]);
    __syncthreads();
  }
#undef STAGE

  // epilogue: bias (+gelu) -> swizzled LDS [128][128] -> coalesced stores
  u16* osm = (u16*)sm;
  #pragma unroll
  for (int ni = 0; ni < 4; ni++) {
    const int col = wc + ni * 16 + lc;
    const float bb = bias[bn + col];
    const int ckey = col >> 3, clow = col & 7;
    #pragma unroll
    for (int mi = 0; mi < 4; mi++) {
      #pragma unroll
      for (int r = 0; r < 4; r++) {
        const int row = wr + mi * 16 + lch * 4 + r;
        float v = acc[mi][ni][r] + bb;
        if (ACT == 1) v = 0.5f * v * (1.0f + erff(v * 0.70710678118f));
        osm[row * 128 + ((ckey ^ ((row & 7) << 1)) << 3) + clow] = f2bf(v);
      }
    }
  }
  __syncthreads();
  #pragma unroll
  for (int p = 0; p < 8; p++) {
    const int flat = p * 256 + t;
    const int row = flat >> 4, c = flat & 15;
    u16x8 y = *(const u16x8*)&osm[row * 128 + ((c ^ ((row & 7) << 1)) << 3)];
    *(u16x8*)&Ob[(size_t)(bm + row) * N + bn + c * 8] = y;
  }
}

// ---------------------------------------------------------------------------
// Retention v2: swapped-operand 32x32x16 MFMA, P in registers.
// ---------------------------------------------------------------------------
__global__ __launch_bounds__(512) void retention_v2(
    const u16* __restrict__ qkvg, u16* __restrict__ gated) {
  const int S = 2048, DD = 2048;
  const int bh = blockIdx.y, b = bh >> 3, h = bh & 7;
  const int t = threadIdx.x, l = t & 63, w = t >> 6;
  const int lid = l & 31, hi = l >> 5;
  const int wrow = blockIdx.x * 256 + w * 32;
  const int i_q = wrow + lid;

  __shared__ __align__(16) u16 sm[18432];

  const size_t base = (size_t)b * S * DD + (size_t)h * 64;
  const u16* qp = qkvg + base;
  const u16* kp = qkvg + base + 512;
  const u16* vp = qkvg + base + 1024;
  const u16* gp = qkvg + base + 1536;

  const float gamma = 1.0f - exp2f(-5.0f - (float)h);
  const float l2g = log2f(gamma);          // < 0
  const float rowsum = (1.0f - exp2f((float)(i_q + 1) * l2g)) * exp2f(5.0f + (float)h);
  const float ai = exp2f((float)i_q * l2g) * rsqrtf(rowsum);
  float bjc[16];
  #pragma unroll
  for (int r = 0; r < 16; r++) {
    int joff = (r & 3) + 8 * (r >> 2) + 4 * hi;
    bjc[r] = exp2f(-(float)joff * l2g);
  }
  const float E32 = exp2f(-32.0f * l2g);
  const float E64 = E32 * E32;
  float Ejt = 1.0f;

  bf16x8 qf[4];
  #pragma unroll
  for (int ks = 0; ks < 4; ks++)
    qf[ks] = *(const bf16x8*)(qp + (size_t)i_q * DD + ks * 16 + 8 * hi);

  f32x16 accO0, accO1;
  #pragma unroll
  for (int r = 0; r < 16; r++) { accO0[r] = 0.0f; accO1[r] = 0.0f; }
  float den_acc = 0.0f;

  const int krow = t >> 3, kcc = t & 7;
  const u16* kg_src = kp + (size_t)krow * DD + ((kcc ^ (krow & 7)) * 8);
  const int vj = t & 63, vd0 = (t >> 6) * 8;
  const u16* vg_src = vp + (size_t)vj * DD + vd0;

  gl_lds16(kg_src, sm + t * 8);
  {
    u16x8 v0 = *(const u16x8*)vg_src;
    #pragma unroll
    for (int e = 0; e < 8; e++) sm[8192 + (vd0 + e) * 72 + vj] = v0[e];
  }
  __syncthreads();

  int cur = 0;
  for (int jt = 0; jt < S; jt += 64) {
    const int nxt = cur ^ 1;
    const bool pref = (jt + 64 < S);
    u16x8 vreg;
    if (pref) {
      vreg = *(const u16x8*)(vg_src + (size_t)(jt + 64) * DD);
      gl_lds16(kg_src + (size_t)(jt + 64) * DD, sm + nxt * 4096 + t * 8);
    }
    const u16* KsB = sm + cur * 4096;
    const u16* VtB = sm + 8192 + cur * 4608;

    #pragma unroll
    for (int jsub = 0; jsub < 2; jsub++) {
      f32x16 s;
      #pragma unroll
      for (int r = 0; r < 16; r++) s[r] = 0.0f;
      #pragma unroll
      for (int ks = 0; ks < 4; ks++) {
        bf16x8 kf = *(const bf16x8*)&KsB[(jsub * 32 + lid) * 64 +
                                         (((2 * ks + hi) ^ (lid & 7)) * 8)];
        s = MFMA32(kf, qf[ks], s);
      }
      {
        const int js = jt + jsub * 32;
        if (js + 31 <= wrow) {
          float coef = ai * Ejt * (jsub ? E32 : 1.0f);
          #pragma unroll
          for (int r = 0; r < 16; r++) s[r] += coef * bjc[r];
        } else if (js <= wrow + 31) {
          float coef = ai * Ejt * (jsub ? E32 : 1.0f);
          #pragma unroll
          for (int r = 0; r < 16; r++) {
            int j = js + (r & 3) + 8 * (r >> 2) + 4 * hi;
            s[r] += (j <= i_q) ? coef * bjc[r] : 0.0f;
          }
        }
      }
      #pragma unroll
      for (int r = 0; r < 16; r++) den_acc += s[r];
      u32 pk[8];
      #pragma unroll
      for (int q = 0; q < 4; q++) {
        pk[q * 2 + 0] = cvt_pk_bf16(s[4 * q + 0], s[4 * q + 1]);
        pk[q * 2 + 1] = cvt_pk_bf16(s[4 * q + 2], s[4 * q + 3]);
      }
      #pragma unroll
      for (int p = 0; p < 2; p++) {
        u32 own0 = hi ? pk[(2 * p + 1) * 2 + 0] : pk[(2 * p) * 2 + 0];
        u32 own1 = hi ? pk[(2 * p + 1) * 2 + 1] : pk[(2 * p) * 2 + 1];
        u32 snd0 = hi ? pk[(2 * p) * 2 + 0] : pk[(2 * p + 1) * 2 + 0];
        u32 snd1 = hi ? pk[(2 * p) * 2 + 1] : pk[(2 * p + 1) * 2 + 1];
        u32 r0 = __shfl_xor(snd0, 32);
        u32 r1 = __shfl_xor(snd1, 32);
        u32x4 paw;
        paw[0] = hi ? r0 : own0;
        paw[1] = hi ? r1 : own1;
        paw[2] = hi ? own0 : r0;
        paw[3] = hi ? own1 : r1;
        bf16x8 paf = u4_to_bf8(paw);
        const int jsl = jsub * 2 + p;
        bf16x8 vt0 = *(const bf16x8*)&VtB[(lid) * 72 + jsl * 16 + 8 * hi];
        bf16x8 vt1 = *(const bf16x8*)&VtB[(32 + lid) * 72 + jsl * 16 + 8 * hi];
        accO0 = MFMA32(vt0, paf, accO0);
        accO1 = MFMA32(vt1, paf, accO1);
      }
    }

    if (pref) {
      #pragma unroll
      for (int e = 0; e < 8; e++)
        sm[8192 + nxt * 4608 + (vd0 + e) * 72 + vj] = vreg[e];
    }
    Ejt *= E64;
    __syncthreads();
    cur = nxt;
  }

  float den = den_acc + __shfl_xor(den_acc, 32);
  float rden = 1.0f / fmaxf(fabsf(den), 1.0f);
  float o0[16], o1[16];
  float s1 = 0.0f, s2 = 0.0f;
  #pragma unroll
  for (int r = 0; r < 16; r++) {
    o0[r] = accO0[r] * rden; s1 += o0[r]; s2 += o0[r] * o0[r];
    o1[r] = accO1[r] * rden; s1 += o1[r]; s2 += o1[r] * o1[r];
  }
  s1 += __shfl_xor(s1, 32);
  s2 += __shfl_xor(s2, 32);
  float mu = s1 * (1.0f / 64.0f);
  float var = s2 * (1.0f / 64.0f) - mu * mu;
  float rv = rsqrtf(var + 1e-6f);

  u16* Ot = sm + w * 2304;
  #pragma unroll
  for (int r = 0; r < 16; r++) {
    int d = (r & 3) + 8 * (r >> 2) + 4 * hi;
    Ot[lid * 72 + d]      = f2bf((o0[r] - mu) * rv);
    Ot[lid * 72 + 32 + d] = f2bf((o1[r] - mu) * rv);
  }
  {
    const int i2 = l >> 1, half = l & 1;
    const int row = wrow + i2;
    #pragma unroll
    for (int c = 0; c < 4; c++) {
      u16x8 y8 = *(const u16x8*)&Ot[i2 * 72 + half * 32 + c * 8];
      u16x8 g8 = *(const u16x8*)(gp + (size_t)row * DD + half * 32 + c * 8);
      u16x8 o8;
      #pragma unroll
      for (int e = 0; e < 8; e++) {
        float gv = bf2f(g8[e]);
        float sg = gv / (1.0f + __expf(-gv));
        o8[e] = f2bf(bf2f(y8[e]) * sg);
      }
      *(u16x8*)&gated[((size_t)(b * S + row)) * 512 + h * 64 + half * 32 + c * 8] = o8;
    }
  }
}

// ---------------------------------------------------------------------------
// x = LN(A + B) * gam + bet over D=512; A fp32, B bf16. One wave per row.
// ---------------------------------------------------------------------------
__global__ __launch_bounds__(256) void add_ln512(
    const float* __restrict__ A, const u16* __restrict__ Bv,
    const float* __restrict__ gam, const float* __restrict__ bet, float eps,
    float* __restrict__ Of, u16* __restrict__ Ob) {
  int row = blockIdx.x * 4 + (threadIdx.x >> 6);
  int l = threadIdx.x & 63;
  const float* a = A + (size_t)row * 512 + l * 8;
  f32x4 a0 = *(const f32x4*)a, a1 = *(const f32x4*)(a + 4);
  u16x8 cv = *(const u16x8*)(Bv + (size_t)row * 512 + l * 8);
  float x[8];
  #pragma unroll
  for (int e = 0; e < 4; e++) { x[e] = a0[e] + bf2f(cv[e]); x[4 + e] = a1[e] + bf2f(cv[4 + e]); }
  float s = 0.f, s2 = 0.f;
  #pragma unroll
  for (int e = 0; e < 8; e++) { s += x[e]; s2 += x[e] * x[e]; }
  #pragma unroll
  for (int m = 1; m <= 32; m <<= 1) { s += __shfl_xor(s, m); s2 += __shfl_xor(s2, m); }
  float mu = s * (1.0f / 512.0f);
  float var = s2 * (1.0f / 512.0f) - mu * mu;
  float rinv = rsqrtf(var + eps);
  f32x4 g0 = *(const f32x4*)(gam + l * 8), g1 = *(const f32x4*)(gam + l * 8 + 4);
  f32x4 b0 = *(const f32x4*)(bet + l * 8), b1 = *(const f32x4*)(bet + l * 8 + 4);
  f32x4 y0, y1;
  #pragma unroll
  for (int e = 0; e < 4; e++) {
    y0[e] = (x[e] - mu) * rinv * g0[e] + b0[e];
    y1[e] = (x[4 + e] - mu) * rinv * g1[e] + b1[e];
  }
  float* op = Of + (size_t)row * 512 + l * 8;
  *(f32x4*)op = y0;
  *(f32x4*)(op + 4) = y1;
  if (Ob) {
    u16x8 rb_;
    #pragma unroll
    for (int e = 0; e < 4; e++) { rb_[e] = f2bf(y0[e]); rb_[4 + e] = f2bf(y1[e]); }
    *(u16x8*)(Ob + (size_t)row * 512 + l * 8) = rb_;
  }
}

// ---------------------------------------------------------------------------
// In-place sub-LN over FFN=2048 (bf16), eps 1e-6, affine. One wave per row.
// ---------------------------------------------------------------------------
__global__ __launch_bounds__(256) void subln_ffn(
    u16* __restrict__ hbuf, const float* __restrict__ gam, const float* __restrict__ bet) {
  int row = blockIdx.x * 4 + (threadIdx.x >> 6);
  int l = threadIdx.x & 63;
  u16* p = hbuf + (size_t)row * 2048;
  float x[32];
  #pragma unroll
  for (int cch = 0; cch < 4; cch++) {
    u16x8 v = *(const u16x8*)(p + cch * 512 + l * 8);
    #pragma unroll
    for (int e = 0; e < 8; e++) x[cch * 8 + e] = bf2f(v[e]);
  }
  float s = 0.f, s2 = 0.f;
  #pragma unroll
  for (int e = 0; e < 32; e++) { s += x[e]; s2 += x[e] * x[e]; }
  #pragma unroll
  for (int m = 1; m <= 32; m <<= 1) { s += __shfl_xor(s, m); s2 += __shfl_xor(s2, m); }
  float mu = s * (1.0f / 2048.0f);
  float var = s2 * (1.0f / 2048.0f) - mu * mu;
  float rinv = rsqrtf(var + 1e-6f);
  #pragma unroll
  for (int cch = 0; cch < 4; cch++) {
    int col = cch * 512 + l * 8;
    f32x4 g0 = *(const f32x4*)(gam + col), g1 = *(const f32x4*)(gam + col + 4);
    f32x4 b0 = *(const f32x4*)(bet + col), b1 = *(const f32x4*)(bet + col + 4);
    u16x8 o;
    #pragma unroll
    for (int e = 0; e < 4; e++) {
      o[e]     = f2bf((x[cch * 8 + e]     - mu) * rinv * g0[e] + b0[e]);
      o[4 + e] = f2bf((x[cch * 8 + 4 + e] - mu) * rinv * g1[e] + b1[e]);
    }
    *(u16x8*)(p + col) = o;
  }
}

// ---------------------------------------------------------------------------
extern "C" void kernel_launch(void* const* d_in, const int* in_sizes, int n_in,
                              void* d_out, int out_size, void* d_ws, size_t ws_size,
                              hipStream_t stream) {
  const float* src  = (const float*)d_in[0];
  const float* wq   = (const float*)d_in[3];
  const float* bq   = (const float*)d_in[4];
  const float* wk   = (const float*)d_in[5];
  const float* bk   = (const float*)d_in[6];
  const float* wv   = (const float*)d_in[7];
  const float* bv   = (const float*)d_in[8];
  const float* wg   = (const float*)d_in[9];
  const float* bg   = (const float*)d_in[10];
  const float* wo   = (const float*)d_in[11];
  const float* bo   = (const float*)d_in[12];
  const float* fc1w = (const float*)d_in[13];
  const float* fc1b = (const float*)d_in[14];
  const float* fc2w = (const float*)d_in[15];
  const float* fc2b = (const float*)d_in[16];
  const float* lng  = (const float*)d_in[17];
  const float* lnb  = (const float*)d_in[18];
  const float* n0g  = (const float*)d_in[19];
  const float* n0b  = (const float*)d_in[20];
  const float* n1g  = (const float*)d_in[21];
  const float* n1b  = (const float*)d_in[22];

  if (ws_size < 90710016u) return;  // need ~90.7 MB scratch

  char* ws = (char*)d_ws;
  u16*   src_bf = (u16*)(ws + 0);
  u16*   Wcat   = (u16*)(ws + 8388608);
  u16*   wo_bf  = (u16*)(ws + 10485760);
  u16*   fc1_bf = (u16*)(ws + 11010048);
  u16*   fc2_bf = (u16*)(ws + 13107200);
  float* bcat   = (float*)(ws + 15204352);
  u16*   qkvg   = (u16*)(ws + 15212544);   // 32 MB; reused as h1 after retention
  u16*   gated  = (u16*)(ws + 48766976);   // 8 MB
  u16*   attn   = (u16*)(ws + 57155584);   // 8 MB; reused as y (fc2 out)
  float* xf     = (float*)(ws + 65544192); // 16 MB
  u16*   xbf    = (u16*)(ws + 82321408);   // 8 MB

  // 1. casts / weight concat
  prep_cast<<<3713, 256, 0, stream>>>(src, wq, wk, wv, wg, wo, fc1w, fc2w,
                                      bq, bk, bv, bg,
                                      src_bf, Wcat, wo_bf, fc1_bf, fc2_bf, bcat);
  // 2. QKVG projection: (8192x512) @ (2048x512)^T
  gemm_v3<0><<<1024, 256, 0, stream>>>(src_bf, Wcat, bcat, qkvg, 2048, 512, 16);
  // 3. retention + per-head LN + silu gating
  retention_v2<<<dim3(8, 32), 512, 0, stream>>>(qkvg, gated);
  // 4. output projection (8192x512 @ 512x512^T)
  gemm_v3<0><<<256, 256, 0, stream>>>(gated, wo_bf, bo, attn, 512, 512, 4);
  // 5. x = LN(src + attn), n0, eps 1e-5 -> fp32 + bf16
  add_ln512<<<2048, 256, 0, stream>>>(src, attn, n0g, n0b, 1e-5f, xf, xbf);
  // 6. fc1 + exact gelu -> h1 (aliases qkvg)
  gemm_v3<1><<<1024, 256, 0, stream>>>(xbf, fc1_bf, fc1b, qkvg, 2048, 512, 16);
  // 7. sub-LN over 2048 (in place)
  subln_ffn<<<2048, 256, 0, stream>>>(qkvg, lng, lnb);
  // 8. fc2 -> y (aliases attn)
  gemm_v3<0><<<256, 256, 0, stream>>>(qkvg, fc2_bf, fc2b, attn, 512, 2048, 4);
  // 9. out = LN(x + y), n1, eps 1e-5 -> d_out (fp32)
  add_ln512<<<2048, 256, 0, stream>>>(xf, attn, n1g, n1b, 1e-5f, (float*)d_out, nullptr);
}